// Round 4
// baseline (301.440 us; speedup 1.0000x reference)
//
#include <hip/hip_runtime.h>
#include <hip/hip_bf16.h>
#include <math.h>

typedef short short8 __attribute__((ext_vector_type(8)));
typedef short short4v __attribute__((ext_vector_type(4)));
typedef float f32x4 __attribute__((ext_vector_type(4)));
typedef __hip_bfloat16 bf16;

// problem constants
#define KN 10
#define KC 512
#define KHW 1600
#define KH 40
#define KOC 128
#define KPW 42   // padded spatial (40+2)
#define KM 1280  // stacked M: 9 conv taps * 128 + 128 shortcut

// direct global->LDS DMA, 16B per lane. LDS dest must be wave-uniform base + lane*16.
__device__ __forceinline__ void gload16(const void* g, void* l) {
  __builtin_amdgcn_global_load_lds(
      (const __attribute__((address_space(1))) unsigned int*)g,
      (__attribute__((address_space(3))) unsigned int*)l, 16, 0, 0);
}

// ---------------- block reduction helpers (fp64) ----------------
__device__ __forceinline__ double blockReduceSumD(double v) {
  __shared__ double tmpS[8];
  int lane = threadIdx.x & 63, wv = threadIdx.x >> 6;
  #pragma unroll
  for (int o = 32; o > 0; o >>= 1) v += __shfl_down(v, o);
  if (lane == 0) tmpS[wv] = v;
  __syncthreads();
  if (threadIdx.x == 0) {
    int nw = (blockDim.x + 63) >> 6;
    double s = 0;
    for (int i = 0; i < nw; i++) s += tmpS[i];
    tmpS[0] = s;
  }
  __syncthreads();
  double r = tmpS[0];
  __syncthreads();
  return r;
}

__device__ __forceinline__ double blockReduceMinD(double v) {
  __shared__ double tmpMn[8];
  int lane = threadIdx.x & 63, wv = threadIdx.x >> 6;
  #pragma unroll
  for (int o = 32; o > 0; o >>= 1) v = fmin(v, __shfl_down(v, o));
  if (lane == 0) tmpMn[wv] = v;
  __syncthreads();
  if (threadIdx.x == 0) {
    int nw = (blockDim.x + 63) >> 6;
    double s = tmpMn[0];
    for (int i = 1; i < nw; i++) s = fmin(s, tmpMn[i]);
    tmpMn[0] = s;
  }
  __syncthreads();
  double r = tmpMn[0];
  __syncthreads();
  return r;
}

__device__ __forceinline__ double blockReduceMaxD(double v) {
  __shared__ double tmpMx[8];
  int lane = threadIdx.x & 63, wv = threadIdx.x >> 6;
  #pragma unroll
  for (int o = 32; o > 0; o >>= 1) v = fmax(v, __shfl_down(v, o));
  if (lane == 0) tmpMx[wv] = v;
  __syncthreads();
  if (threadIdx.x == 0) {
    int nw = (blockDim.x + 63) >> 6;
    double s = tmpMx[0];
    for (int i = 1; i < nw; i++) s = fmax(s, tmpMx[i]);
    tmpMx[0] = s;
  }
  __syncthreads();
  double r = tmpMx[0];
  __syncthreads();
  return r;
}

// ---------------- small chain (fp64 for argsort stability) ----------------

__global__ void k_rnormp(const float* __restrict__ feats, double* __restrict__ ps) {
  int t = blockIdx.x * 256 + threadIdx.x;
  if (t >= KN * KHW) return;
  int ci = blockIdx.y;
  int n = t / KHW, k = t % KHW;
  const float* p = feats + (size_t)n * KC * KHW + (size_t)ci * 128 * KHW + k;
  double s = 0.0;
  for (int c = 0; c < 128; ++c) { double v = p[(size_t)c * KHW]; s += v * v; }
  ps[(size_t)ci * KN * KHW + t] = s;
}

__global__ void k_rnormc(const double* __restrict__ ps, double* __restrict__ rnorm) {
  int t = blockIdx.x * 256 + threadIdx.x;
  if (t >= KN * KHW) return;
  double s = ps[t] + ps[KN * KHW + t] + ps[2 * KN * KHW + t] + ps[3 * KN * KHW + t];
  double nn = sqrt(s);
  if (nn < 1e-12) nn = 1e-12;
  rnorm[t] = 1.0 / nn;
}

// NFT[n,k,c] = bf16(feats[n,c,k] * rnorm[n,k]); also emits SIV pre-partials
__global__ void k_nft(const float* __restrict__ feats, const double* __restrict__ rnorm,
                      const float* __restrict__ sism, bf16* __restrict__ NFT,
                      double* __restrict__ vpp) {
  __shared__ float T[32][33];
  int n = blockIdx.z, k0 = blockIdx.x * 32, c0 = blockIdx.y * 32;
  int tx = threadIdx.x, ty = threadIdx.y;
  const float* fb = feats + ((size_t)n * KC + c0) * KHW + k0;
  #pragma unroll
  for (int ii = 0; ii < 4; ii++) {
    int cl = ty * 4 + ii;
    T[cl][tx] = fb[(size_t)cl * KHW + tx];
  }
  __syncthreads();
  bf16* ob = NFT + ((size_t)n * KHW + k0) * KC + c0;
  #pragma unroll
  for (int ii = 0; ii < 4; ii++) {
    int kl = ty * 4 + ii;
    float r = (float)rnorm[n * KHW + k0 + kl];
    ob[(size_t)kl * KC + tx] = __float2bfloat16(T[tx][kl] * r);
  }
  double rs = rnorm[n * KHW + k0 + tx] * (double)sism[n * KHW + k0 + tx];
  #pragma unroll
  for (int ii = 0; ii < 4; ii++) {
    int cl = ty * 4 + ii;
    double v = (double)T[cl][tx] * rs;
    #pragma unroll
    for (int o = 16; o > 0; o >>= 1) v += __shfl_down(v, o, 32);
    if (tx == 0) vpp[((size_t)n * KC + c0 + cl) * 50 + k0 / 32] = v;
  }
}

__global__ void k_sivnorm2(const double* __restrict__ vpp, double* __restrict__ SIV) {
  int n = blockIdx.x, c = threadIdx.x;   // 512 threads
  const double* p = vpp + ((size_t)n * KC + c) * 50;
  double acc = 0;
  #pragma unroll 5
  for (int j = 0; j < 50; j++) acc += p[j];
  acc /= (double)KHW;
  double s2 = blockReduceSumD(acc * acc);
  double nn = sqrt(s2);
  if (nn < 1e-12) nn = 1e-12;
  SIV[n * KC + c] = acc / nn;
}

__global__ void k_cmP(const float* __restrict__ feats, const double* __restrict__ SIV,
                      double* __restrict__ cmp) {
  __shared__ double sv[KN][64];
  int kc = blockIdx.x, ci = blockIdx.y, n = blockIdx.z;
  for (int t = threadIdx.x; t < KN * 64; t += 256) {
    int m = t / 64, c = t % 64;
    sv[m][c] = SIV[m * KC + ci * 64 + c];
  }
  __syncthreads();
  int k = kc * 256 + threadIdx.x;
  if (k >= KHW) return;
  const float* f = feats + ((size_t)n * KC + ci * 64) * KHW + k;
  double acc[KN];
  #pragma unroll
  for (int m = 0; m < KN; m++) acc[m] = 0.0;
  for (int c = 0; c < 64; ++c) {
    double fv = f[(size_t)c * KHW];
    #pragma unroll
    for (int m = 0; m < KN; m++) acc[m] += fv * sv[m][c];
  }
  const size_t str = (size_t)KN * KN * KHW;
  #pragma unroll
  for (int m = 0; m < KN; m++)
    cmp[(size_t)ci * str + ((size_t)n * KN + m) * KHW + k] = acc[m];
}

__global__ void k_cmB(const double* __restrict__ cmp, const double* __restrict__ rnorm,
                      double* __restrict__ cm) {
  size_t t = (size_t)blockIdx.x * 256 + threadIdx.x;
  if (t >= (size_t)KN * KN * KHW) return;
  int k = t % KHW;
  int n = (int)(t / ((size_t)KN * KHW));
  const size_t str = (size_t)KN * KN * KHW;
  double s = 0;
  #pragma unroll
  for (int ci = 0; ci < 8; ci++) s += cmp[ci * str + t];
  cm[t] = s * rnorm[n * KHW + k];
}

__global__ void k_cmnorm(double* __restrict__ cm) {
  double* row = cm + (size_t)blockIdx.x * KHW;
  double s = 0;
  for (int k = threadIdx.x; k < KHW; k += 256) { double v = row[k]; s += v * v; }
  s = blockReduceSumD(s);
  double nn = sqrt(s);
  if (nn < 1e-12) nn = 1e-12;
  double rn = 1.0 / nn;
  for (int k = threadIdx.x; k < KHW; k += 256) row[k] *= rn;
}

__global__ void k_st(const double* __restrict__ cm, double* __restrict__ tbuf) {
  int b = blockIdx.x;
  int n = b / KN, m = b % KN;
  const double* base = cm + (size_t)n * KN * KHW;
  double acc = 0;
  for (int k = threadIdx.x; k < KHW; k += 256) {
    double S = 0;
    #pragma unroll
    for (int mm = 0; mm < KN; mm++) S += base[(size_t)mm * KHW + k];
    acc += base[(size_t)m * KHW + k] * S;
  }
  acc = blockReduceSumD(acc);
  if (threadIdx.x == 0) tbuf[b] = acc;
}

__global__ void k_csa(const double* __restrict__ cm, const double* __restrict__ tbuf,
                      double* __restrict__ CSAd, float* __restrict__ CSAf) {
  __shared__ double w[KN];
  int n = blockIdx.x, tid = threadIdx.x;
  if (tid == 0) {
    double v[KN], mx = -1e300;
    #pragma unroll
    for (int m = 0; m < KN; m++) { v[m] = tbuf[n * KN + m]; mx = fmax(mx, v[m]); }
    double s = 0;
    #pragma unroll
    for (int m = 0; m < KN; m++) { v[m] = exp(v[m] - mx); s += v[m]; }
    #pragma unroll
    for (int m = 0; m < KN; m++) w[m] = v[m] / s;
  }
  __syncthreads();
  double v[7];
  int cnt = 0;
  double lmin = 1e300, lmax = -1e300;
  for (int k = tid; k < KHW; k += 256) {
    double a = 0;
    #pragma unroll
    for (int m = 0; m < KN; m++) a += cm[((size_t)n * KN + m) * KHW + k] * w[m];
    v[cnt++] = a;
    lmin = fmin(lmin, a);
    lmax = fmax(lmax, a);
  }
  double mn = blockReduceMinD(lmin);
  double mx = blockReduceMaxD(lmax);
  double inv = 1.0 / (mx - mn + 1e-12);
  cnt = 0;
  for (int k = tid; k < KHW; k += 256) {
    double nv = (v[cnt++] - mn) * inv;
    CSAd[(size_t)n * KHW + k] = nv;
    CSAf[(size_t)n * KHW + k] = (float)nv;
  }
}

// rank-based stable descending argsort: idx[rank[i]] = i
// wave-parallel: 1000 blocks; block = 16 i's (4 waves x 4), lanes cover j.
__global__ void k_rank(const double* __restrict__ CSAd, int* __restrict__ idx) {
  __shared__ double key[KHW];
  int b = blockIdx.x;
  int n = b / 100, it = b % 100;
  const double* src = CSAd + (size_t)n * KHW;
  for (int j = threadIdx.x; j < KHW; j += 256) key[j] = src[j];
  __syncthreads();
  int wave = threadIdx.x >> 6, lane = threadIdx.x & 63;
  int i0 = it * 16 + wave * 4;
  double ki[4];
  #pragma unroll
  for (int ii = 0; ii < 4; ii++) ki[ii] = key[i0 + ii];
  int r[4] = {0, 0, 0, 0};
  #pragma unroll
  for (int q = 0; q < 25; q++) {
    int j = q * 64 + lane;
    double kj = key[j];
    #pragma unroll
    for (int ii = 0; ii < 4; ii++) {
      int i = i0 + ii;
      r[ii] += (kj > ki[ii]) || (kj == ki[ii] && j < i);
    }
  }
  #pragma unroll
  for (int ii = 0; ii < 4; ii++) {
    int v = r[ii];
    #pragma unroll
    for (int o = 32; o > 0; o >>= 1) v += __shfl_down(v, o);
    if (lane == 0) idx[n * KHW + v] = i0 + ii;
  }
}

// ---------------- stacked weights (n-independent): w1s[(tau,o)][i] ----------------
__global__ void k_prepw1s(const float* __restrict__ w1, const float* __restrict__ wsc,
                          bf16* __restrict__ w1s) {
  int t = blockIdx.x * 256 + threadIdx.x;   // over KM*KHW
  int m = t / KHW, i = t % KHW;
  int tau = m >> 7, o = m & 127;
  float v = (tau < 9) ? w1[((size_t)o * KHW + i) * 9 + tau]
                      : wsc[(size_t)o * KHW + i];
  w1s[t] = __float2bfloat16(v);
}

__global__ void k_prepw2(const float* __restrict__ w2, bf16* __restrict__ w2p) {
  int t = blockIdx.x * 256 + threadIdx.x;
  if (t >= KOC * 9 * KOC) return;
  int o = t / (9 * KOC), r = t % (9 * KOC);
  int s = r / KOC, i = r % KOC;
  w2p[t] = __float2bfloat16(w2[(size_t)o * 9 * KOC + (size_t)i * 9 + s]);
}

// ---------------- NF column gather: NFcg[n][c][i] = NFT[n][idx[i]][c] ----------------
__global__ void k_gath2(const short* __restrict__ NFT, const int* __restrict__ idx,
                        short* __restrict__ NFcg) {
  __shared__ short T[32][33];
  int i0 = blockIdx.x * 32, c0 = blockIdx.y * 32, n = blockIdx.z;
  int tx = threadIdx.x, ty = threadIdx.y;
  #pragma unroll
  for (int ii = 0; ii < 4; ii++) {
    int row = ty * 4 + ii;
    int id = idx[n * KHW + i0 + row];
    T[row][tx] = NFT[((size_t)n * KHW + id) * KC + c0 + tx];
  }
  __syncthreads();
  #pragma unroll
  for (int ii = 0; ii < 4; ii++) {
    int cl = ty * 4 + ii;
    NFcg[((size_t)n * KC + c0 + cl) * KHW + i0 + tx] = T[tx][cl];
  }
}

// Zpad[n, y+1, x+1, c] = bf16(NFT[n,p,c] * CSA[n,p])
__global__ void k_zprep(const bf16* __restrict__ NFT, const float* __restrict__ CSAf,
                        bf16* __restrict__ Zpad) {
  int t = blockIdx.x * 256 + threadIdx.x;   // over KN*KHW*KC/4
  const int per_n = KHW * (KC / 4);
  int n = t / per_n, r = t % per_n;
  int p = r / (KC / 4), cq = r % (KC / 4);
  float cs = CSAf[n * KHW + p];
  const short* src = (const short*)(NFT + ((size_t)n * KHW + p) * KC) + cq * 4;
  short4v v = *(const short4v*)src;
  short4v o;
  #pragma unroll
  for (int j = 0; j < 4; j++) {
    short s = v[j];
    bf16 hb = *reinterpret_cast<bf16*>(&s);
    bf16 res = __float2bfloat16(__bfloat162float(hb) * cs);
    o[j] = *reinterpret_cast<short*>(&res);
  }
  int y = p / KH, x = p % KH;
  short* dst = (short*)(Zpad + ((size_t)n * KPW * KPW + (size_t)(y + 1) * KPW + (x + 1)) * KC) + cq * 4;
  *(short4v*)dst = o;
}

// ---------------- GEMM1: U = w1s x NFcg, conv layout; XCD-swizzled 1D grid ----------------
__global__ __launch_bounds__(256) void k_gemmU(const short* __restrict__ w1s,
                                               const short* __restrict__ NFcg,
                                               bf16* __restrict__ Uc,
                                               bf16* __restrict__ Usc) {
  __shared__ __align__(16) short smem[8704];   // As[64][32] | Bs[128][32]; reused as Cs[64][136]
  short* As = smem;                            // 2048 shorts
  short* Bs = smem + 2048;                     // 4096 shorts
  short* Cs = smem;
  int b = blockIdx.x;
  int workid = (b & 7) * 100 + (b >> 3);       // XCD-contiguous work ids (bijective, 800 % 8 == 0)
  int pair = workid / 20;                      // 0..39 : (n, c0 tile)
  int th = workid % 20;                        // 0..19 : (tau, half)
  int n = pair >> 2, c0 = (pair & 3) * 128;
  int tau = th >> 1, half = th & 1;
  int m0 = tau * 128 + half * 64;
  int tid = threadIdx.x, lane = tid & 63, wave = tid >> 6;
  int quad = lane >> 4, l15 = lane & 15;
  int wm = (wave & 1) * 32, wn = (wave >> 1) * 64;
  int ar = tid >> 2, ko = (tid & 3) * 8;
  const short* Bb = NFcg + (size_t)n * KC * KHW;
  const short* pa0 = w1s + (size_t)(m0 + ar) * KHW + ko;
  const short* pb0 = Bb + (size_t)(c0 + ar) * KHW + ko;
  const short* pb1 = Bb + (size_t)(c0 + ar + 64) * KHW + ko;
  char* dA  = (char*)As + tid * 16;            // == (tid>>2)*64 + (tid&3)*16, lane-linear
  char* dB0 = (char*)Bs + tid * 16;
  char* dB1 = (char*)Bs + 4096 + tid * 16;
  f32x4 acc[2][4] = {};
  for (int k0 = 0; k0 < KHW; k0 += 32) {
    __syncthreads();
    gload16(pa0 + k0, dA);
    gload16(pb0 + k0, dB0);
    gload16(pb1 + k0, dB1);
    __syncthreads();                           // drains vmcnt: tile ready
    short8 a[2], bb[4];
    #pragma unroll
    for (int t = 0; t < 2; t++) a[t] = *(const short8*)&As[(wm + t * 16 + l15) * 32 + quad * 8];
    #pragma unroll
    for (int t = 0; t < 4; t++) bb[t] = *(const short8*)&Bs[(wn + t * 16 + l15) * 32 + quad * 8];
    #pragma unroll
    for (int ti = 0; ti < 2; ti++)
      #pragma unroll
      for (int tj = 0; tj < 4; tj++)
        acc[ti][tj] = __builtin_amdgcn_mfma_f32_16x16x32_bf16(a[ti], bb[tj], acc[ti][tj], 0, 0, 0);
  }
  __syncthreads();   // frag reads done; reuse smem as Cs
  #pragma unroll
  for (int ti = 0; ti < 2; ti++) {
    int lr = wm + ti * 16 + quad * 4;
    #pragma unroll
    for (int tj = 0; tj < 4; tj++) {
      int lc = wn + tj * 16 + l15;
      #pragma unroll
      for (int r = 0; r < 4; r++)
        *(bf16*)&Cs[(lr + r) * 136 + lc] = __float2bfloat16(acc[ti][tj][r]);
    }
  }
  __syncthreads();
  int dyq = tau / 3, dxq = tau % 3;
  #pragma unroll
  for (int pass = 0; pass < 4; pass++) {
    int row = pass * 16 + (tid >> 4);          // 0..63
    int col = (tid & 15) * 8;                  // 0..127
    if (tau < 9) {
      *(float4*)&Uc[((size_t)((n * 3 + dyq) * 128 + half * 64 + row)) * 1536 + dxq * 512 + c0 + col] =
          *(const float4*)&Cs[row * 136 + col];
    } else {
      *(float4*)&Usc[((size_t)(n * 128 + half * 64 + row)) * 512 + c0 + col] =
          *(const float4*)&Cs[row * 136 + col];
    }
  }
}

// ---------------- convh: dy-split pipelined GEMM, M=128(o) x N=64(p), K=1536 (conv) / 512 (sc)
// 1000 blocks = 10n * 4dy * 25pt, XCD-chunked swizzle. Double-buffered LDS via global_load_lds
// with pre-swizzled source (T2) and counted vmcnt (T4). For fixed dy, both Uc rows and Zpad
// rows are K-contiguous (x-stride == 512), so per-step offset is simply s*64.
__global__ __launch_bounds__(256) void k_convh(const short* __restrict__ Uc,
                                               const short* __restrict__ Usc,
                                               const short* __restrict__ Zpad,
                                               float* __restrict__ Hpart) {
  __shared__ __align__(16) short smem[24576];  // As[2][8192] | Bs[2][4096]  (48 KB)
  short* As = smem;
  short* Bs = smem + 16384;
  int b = blockIdx.x;
  int wgid = (b & 7) * 125 + (b >> 3);         // bijective, 1000 % 8 == 0
  int n = wgid / 100, rest = wgid % 100;
  int dy = rest / 25, pt = rest % 25;
  int p0 = pt * 64;
  int tid = threadIdx.x, lane = tid & 63, wave = tid >> 6;
  int quad = lane >> 4, l15 = lane & 15;
  int wm = (wave & 1) * 64, wn = (wave >> 1) * 32;
  // staging: pre-swizzled global source; LDS stays linear (rule #21)
  int sk = ((tid & 7) ^ ((tid >> 3) & 7)) * 8;   // swizzled 16B-chunk (shorts)
  int rowg = tid >> 3;                            // 0..31
  bool isconv = (dy < 3);
  const short* Zb = Zpad + (size_t)n * KPW * KPW * KC;
  const short* Abase = isconv ? Uc + ((size_t)((n * 3 + dy) * 128)) * 1536
                              : Usc + ((size_t)(n * 128)) * 512;
  int astr = isconv ? 1536 : 512;
  const short* pA[4];
  #pragma unroll
  for (int g = 0; g < 4; g++)
    pA[g] = Abase + (size_t)(g * 32 + rowg) * astr + sk;
  const short* pB[2];
  #pragma unroll
  for (int g = 0; g < 2; g++) {
    int p = p0 + g * 32 + rowg;
    int y = p / KH, x = p % KH;
    int yy = isconv ? (y + dy) : (y + 1);
    int xx = isconv ? x : (x + 1);
    pB[g] = Zb + ((size_t)yy * KPW + xx) * KC + sk;
  }
  char* lA = (char*)As + tid * 16;
  char* lB = (char*)Bs + tid * 16;
  int NS = isconv ? 24 : 8;
  // swizzled ds_read k offsets (shorts)
  int bq = (l15 >> 2) & 1;
  int qx = (quad ^ (l15 & 3)) * 8;
  int koff0 = 32 * bq + qx;
  int koff1 = 32 * (1 - bq) + qx;
  f32x4 acc[4][2] = {};
  // prologue: stage step 0 into buf 0
  gload16(pA[0], lA); gload16(pA[1], lA + 4096);
  gload16(pA[2], lA + 8192); gload16(pA[3], lA + 12288);
  gload16(pB[0], lB); gload16(pB[1], lB + 4096);
  for (int s = 0; s < NS; s++) {
    int cb = s & 1, nb = cb ^ 1;
    if (s + 1 < NS) {
      int off = (s + 1) * 64;
      char* la = lA + nb * 16384;
      char* lb = lB + nb * 8192;
      gload16(pA[0] + off, la); gload16(pA[1] + off, la + 4096);
      gload16(pA[2] + off, la + 8192); gload16(pA[3] + off, la + 12288);
      gload16(pB[0] + off, lb); gload16(pB[1] + off, lb + 4096);
      asm volatile("s_waitcnt vmcnt(6)" ::: "memory");   // current buf done; next 6 in flight
    } else {
      asm volatile("s_waitcnt vmcnt(0)" ::: "memory");
    }
    __builtin_amdgcn_s_barrier();
    __builtin_amdgcn_sched_barrier(0);
    const short* Ab = As + cb * 8192;
    const short* Bb = Bs + cb * 4096;
    #pragma unroll
    for (int ks = 0; ks < 2; ks++) {
      int ko = (ks == 0) ? koff0 : koff1;
      short8 av[4], bv[2];
      #pragma unroll
      for (int t = 0; t < 4; t++) av[t] = *(const short8*)&Ab[(wm + t * 16 + l15) * 64 + ko];
      #pragma unroll
      for (int t = 0; t < 2; t++) bv[t] = *(const short8*)&Bb[(wn + t * 16 + l15) * 64 + ko];
      #pragma unroll
      for (int ti = 0; ti < 4; ti++)
        #pragma unroll
        for (int tj = 0; tj < 2; tj++)
          acc[ti][tj] = __builtin_amdgcn_mfma_f32_16x16x32_bf16(av[ti], bv[tj], acc[ti][tj], 0, 0, 0);
    }
    __builtin_amdgcn_s_barrier();              // lgkm drained before MFMA; safe to overwrite cb
  }
  float* cbp = Hpart + ((size_t)(dy * KN + n)) * KOC * KHW;
  #pragma unroll
  for (int ti = 0; ti < 4; ti++) {
    int o = wm + ti * 16 + quad * 4;
    #pragma unroll
    for (int tj = 0; tj < 2; tj++) {
      int q = p0 + wn + tj * 16 + l15;
      #pragma unroll
      for (int r = 0; r < 4; r++)
        cbp[(size_t)(o + r) * KHW + q] = acc[ti][tj][r];
    }
  }
}

// hpadT[n, y+1, x+1, o] = bf16(relu(b1[o] + Hpart[0]+Hpart[1]+Hpart[2]))
__global__ void k_hprep3(const float* __restrict__ Hpart, const float* __restrict__ b1,
                         bf16* __restrict__ hpadT) {
  __shared__ float T[32][132];
  int n = blockIdx.y, p0 = blockIdx.x * 32;
  int tx = threadIdx.x, ty = threadIdx.y;
  const size_t str = (size_t)KN * KOC * KHW;
  const float* hb = Hpart + (size_t)n * KOC * KHW;
  #pragma unroll
  for (int oc = 0; oc < 16; oc++) {
    int o = oc * 8 + ty;
    size_t off = (size_t)o * KHW + p0 + tx;
    T[tx][o] = fmaxf(hb[off] + hb[str + off] + hb[2 * str + off] + b1[o], 0.0f);
  }
  __syncthreads();
  bf16* hp = hpadT + (size_t)n * KPW * KPW * KOC;
  #pragma unroll
  for (int pc = 0; pc < 4; pc++) {
    int pl = ty * 4 + pc;
    int pp = p0 + pl;
    int yy = pp / KH, xx = pp % KH;
    bf16* row = hp + ((size_t)(yy + 1) * KPW + (xx + 1)) * KOC;
    #pragma unroll
    for (int u = 0; u < 4; u++) row[tx * 4 + u] = __float2bfloat16(T[pl][tx * 4 + u]);
  }
}

// ---------------- conv2 (3x3, 128->128): same pipelined template, K=384 per dy ----------------
// 750 blocks = 10n * 3dy * 25pt, bijective XCD swizzle (750 = 8*93+6).
__global__ __launch_bounds__(256) void k_conv2(const short* __restrict__ w2p,
                                               const short* __restrict__ hpadT,
                                               float* __restrict__ Cpart) {
  __shared__ __align__(16) short smem[24576];
  short* As = smem;
  short* Bs = smem + 16384;
  int b = blockIdx.x;
  int xcd = b & 7, bi = b >> 3;
  int wgid = (xcd < 6 ? xcd * 94 : 6 * 94 + (xcd - 6) * 93) + bi;
  int n = wgid / 75, rest = wgid % 75;
  int dy = rest / 25, pt = rest % 25;
  int p0 = pt * 64;
  int tid = threadIdx.x, lane = tid & 63, wave = tid >> 6;
  int quad = lane >> 4, l15 = lane & 15;
  int wm = (wave & 1) * 64, wn = (wave >> 1) * 32;
  int sk = ((tid & 7) ^ ((tid >> 3) & 7)) * 8;
  int rowg = tid >> 3;
  const short* hb = hpadT + (size_t)n * KPW * KPW * KOC;
  const short* pA[4];
  #pragma unroll
  for (int g = 0; g < 4; g++)
    pA[g] = w2p + (size_t)(g * 32 + rowg) * (9 * KOC) + dy * 384 + sk;
  const short* pB[2];
  #pragma unroll
  for (int g = 0; g < 2; g++) {
    int p = p0 + g * 32 + rowg;
    int y = p / KH, x = p % KH;
    pB[g] = hb + ((size_t)(y + dy) * KPW + x) * KOC + sk;   // k = dx*128+c contiguous
  }
  char* lA = (char*)As + tid * 16;
  char* lB = (char*)Bs + tid * 16;
  const int NS = 6;                            // K = 384 = 6 * 64
  int bq = (l15 >> 2) & 1;
  int qx = (quad ^ (l15 & 3)) * 8;
  int koff0 = 32 * bq + qx;
  int koff1 = 32 * (1 - bq) + qx;
  f32x4 acc[4][2] = {};
  gload16(pA[0], lA); gload16(pA[1], lA + 4096);
  gload16(pA[2], lA + 8192); gload16(pA[3], lA + 12288);
  gload16(pB[0], lB); gload16(pB[1], lB + 4096);
  for (int s = 0; s < NS; s++) {
    int cb = s & 1, nb = cb ^ 1;
    if (s + 1 < NS) {
      int off = (s + 1) * 64;
      char* la = lA + nb * 16384;
      char* lb = lB + nb * 8192;
      gload16(pA[0] + off, la); gload16(pA[1] + off, la + 4096);
      gload16(pA[2] + off, la + 8192); gload16(pA[3] + off, la + 12288);
      gload16(pB[0] + off, lb); gload16(pB[1] + off, lb + 4096);
      asm volatile("s_waitcnt vmcnt(6)" ::: "memory");
    } else {
      asm volatile("s_waitcnt vmcnt(0)" ::: "memory");
    }
    __builtin_amdgcn_s_barrier();
    __builtin_amdgcn_sched_barrier(0);
    const short* Ab = As + cb * 8192;
    const short* Bb = Bs + cb * 4096;
    #pragma unroll
    for (int ks = 0; ks < 2; ks++) {
      int ko = (ks == 0) ? koff0 : koff1;
      short8 av[4], bv[2];
      #pragma unroll
      for (int t = 0; t < 4; t++) av[t] = *(const short8*)&Ab[(wm + t * 16 + l15) * 64 + ko];
      #pragma unroll
      for (int t = 0; t < 2; t++) bv[t] = *(const short8*)&Bb[(wn + t * 16 + l15) * 64 + ko];
      #pragma unroll
      for (int ti = 0; ti < 4; ti++)
        #pragma unroll
        for (int tj = 0; tj < 2; tj++)
          acc[ti][tj] = __builtin_amdgcn_mfma_f32_16x16x32_bf16(av[ti], bv[tj], acc[ti][tj], 0, 0, 0);
    }
    __builtin_amdgcn_s_barrier();
  }
  float* cbp = Cpart + ((size_t)(dy * KN + n)) * KOC * KHW;
  #pragma unroll
  for (int ti = 0; ti < 4; ti++) {
    int o = wm + ti * 16 + quad * 4;
    #pragma unroll
    for (int tj = 0; tj < 2; tj++) {
      int q = p0 + wn + tj * 16 + l15;
      #pragma unroll
      for (int r = 0; r < 4; r++)
        cbp[(size_t)(o + r) * KHW + q] = acc[ti][tj][r];
    }
  }
}

// out = relu(sum_dy Cpart + b2 + shortcut(Hpart[3]) + bs)
__global__ void k_final2(const float* __restrict__ Cpart, const float* __restrict__ Hpart,
                         const float* __restrict__ b2, const float* __restrict__ bs,
                         float* __restrict__ out) {
  int t = blockIdx.x * 256 + threadIdx.x;
  if (t >= KN * KOC * KHW) return;
  int o = (t / KHW) % KOC;
  const size_t stride = (size_t)KN * KOC * KHW;
  float v = Cpart[t] + Cpart[stride + t] + Cpart[2 * stride + t] +
            Hpart[3 * stride + t] + b2[o] + bs[o];
  out[t] = fmaxf(v, 0.0f);
}

// ---------------- launch ----------------
extern "C" void kernel_launch(void* const* d_in, const int* in_sizes, int n_in,
                              void* d_out, int out_size, void* d_ws, size_t ws_size,
                              hipStream_t stream) {
  const float* feats = (const float*)d_in[0];
  const float* sisms = (const float*)d_in[1];
  const float* w1 = (const float*)d_in[2];
  const float* b1 = (const float*)d_in[3];
  const float* w2 = (const float*)d_in[4];
  const float* b2 = (const float*)d_in[5];
  const float* wsc = (const float*)d_in[6];
  const float* bsc = (const float*)d_in[7];
  float* out = (float*)d_out;

  char* w = (char*)d_ws;
  auto carve = [&](size_t bytes) -> void* {
    void* p = (void*)w;
    w += (bytes + 255) & ~(size_t)255;
    return p;
  };
  bf16* NFT   = (bf16*)carve((size_t)KN * KHW * KC * 2);          // 16.4 MB
  bf16* NFcg  = (bf16*)carve((size_t)KN * KC * KHW * 2);          // 16.4 MB
  bf16* Uc    = (bf16*)carve((size_t)KN * 3 * 128 * 1536 * 2);    // 11.8 MB
  bf16* Usc   = (bf16*)carve((size_t)KN * 128 * 512 * 2);         // 1.3 MB
  bf16* w1s   = (bf16*)carve((size_t)KM * KHW * 2);               // 4.1 MB
  bf16* Zpad  = (bf16*)carve((size_t)KN * KPW * KPW * KC * 2);    // 18.1 MB
  bf16* hpadT = (bf16*)carve((size_t)KN * KPW * KPW * KOC * 2);   // 4.5 MB
  float* Hpart = (float*)carve((size_t)4 * KN * KOC * KHW * 4);   // 32.8 MB
  float* Cpart = (float*)carve((size_t)3 * KN * KOC * KHW * 4);   // 24.6 MB
  bf16* w2p   = (bf16*)carve((size_t)KOC * 9 * KOC * 2);
  double* psbuf = (double*)carve((size_t)4 * KN * KHW * 8);
  double* rnorm = (double*)carve((size_t)KN * KHW * 8);
  double* vpp   = (double*)carve((size_t)KN * KC * 50 * 8);       // 2.05 MB
  double* SIV   = (double*)carve((size_t)KN * KC * 8);
  double* cmp   = (double*)carve((size_t)8 * KN * KN * KHW * 8);  // 10.2 MB
  double* cm    = (double*)carve((size_t)KN * KN * KHW * 8);
  double* tbuf  = (double*)carve((size_t)KN * KN * 8);
  double* CSAd  = (double*)carve((size_t)KN * KHW * 8);
  float* CSAf   = (float*)carve((size_t)KN * KHW * 4);
  int* idxb     = (int*)carve((size_t)KN * KHW * 4);

  hipMemsetAsync(hpadT, 0, (size_t)KN * KPW * KPW * KOC * 2, stream);
  hipMemsetAsync(Zpad, 0, (size_t)KN * KPW * KPW * KC * 2, stream);

  k_rnormp<<<dim3(63, 4), 256, 0, stream>>>(feats, psbuf);
  k_rnormc<<<63, 256, 0, stream>>>(psbuf, rnorm);
  k_nft<<<dim3(50, 16, KN), dim3(32, 8), 0, stream>>>(feats, rnorm, sisms, NFT, vpp);
  k_sivnorm2<<<KN, 512, 0, stream>>>(vpp, SIV);
  k_cmP<<<dim3(7, 8, KN), 256, 0, stream>>>(feats, SIV, cmp);
  k_cmB<<<625, 256, 0, stream>>>(cmp, rnorm, cm);
  k_cmnorm<<<KN * KN, 256, 0, stream>>>(cm);
  k_st<<<KN * KN, 256, 0, stream>>>(cm, tbuf);
  k_csa<<<KN, 256, 0, stream>>>(cm, tbuf, CSAd, CSAf);
  k_rank<<<1000, 256, 0, stream>>>(CSAd, idxb);

  k_prepw1s<<<KM * KHW / 256, 256, 0, stream>>>(w1, wsc, w1s);
  k_prepw2<<<576, 256, 0, stream>>>(w2, w2p);
  k_gath2<<<dim3(50, 16, KN), dim3(32, 8), 0, stream>>>((const short*)NFT, idxb, (short*)NFcg);
  k_zprep<<<KN * KHW * (KC / 4) / 256, 256, 0, stream>>>(NFT, CSAf, Zpad);

  k_gemmU<<<800, 256, 0, stream>>>((const short*)w1s, (const short*)NFcg, Uc, Usc);
  k_convh<<<1000, 256, 0, stream>>>((const short*)Uc, (const short*)Usc,
                                    (const short*)Zpad, Hpart);
  k_hprep3<<<dim3(50, KN), dim3(32, 8), 0, stream>>>(Hpart, b1, hpadT);
  k_conv2<<<750, 256, 0, stream>>>((const short*)w2p, (const short*)hpadT, Cpart);
  k_final2<<<8000, 256, 0, stream>>>(Cpart, Hpart, b2, bsc, out);
}

// Round 5
// 285.533 us; speedup vs baseline: 1.0557x; 1.0557x over previous
//
#include <hip/hip_runtime.h>
#include <hip/hip_bf16.h>
#include <math.h>

typedef short short8 __attribute__((ext_vector_type(8)));
typedef short short4v __attribute__((ext_vector_type(4)));
typedef float f32x4 __attribute__((ext_vector_type(4)));
typedef __hip_bfloat16 bf16;

// problem constants
#define KN 10
#define KC 512
#define KHW 1600
#define KH 40
#define KOC 128
#define KPW 42   // padded spatial (40+2)
#define KM 1280  // stacked M: 9 conv taps * 128 + 128 shortcut

// direct global->LDS DMA, 16B per lane. LDS dest must be wave-uniform base + lane*16.
__device__ __forceinline__ void gload16(const void* g, void* l) {
  __builtin_amdgcn_global_load_lds(
      (const __attribute__((address_space(1))) unsigned int*)g,
      (__attribute__((address_space(3))) unsigned int*)l, 16, 0, 0);
}

// ---------------- block reduction helpers (fp64) ----------------
__device__ __forceinline__ double blockReduceSumD(double v) {
  __shared__ double tmpS[8];
  int lane = threadIdx.x & 63, wv = threadIdx.x >> 6;
  #pragma unroll
  for (int o = 32; o > 0; o >>= 1) v += __shfl_down(v, o);
  if (lane == 0) tmpS[wv] = v;
  __syncthreads();
  if (threadIdx.x == 0) {
    int nw = (blockDim.x + 63) >> 6;
    double s = 0;
    for (int i = 0; i < nw; i++) s += tmpS[i];
    tmpS[0] = s;
  }
  __syncthreads();
  double r = tmpS[0];
  __syncthreads();
  return r;
}

__device__ __forceinline__ double blockReduceMinD(double v) {
  __shared__ double tmpMn[8];
  int lane = threadIdx.x & 63, wv = threadIdx.x >> 6;
  #pragma unroll
  for (int o = 32; o > 0; o >>= 1) v = fmin(v, __shfl_down(v, o));
  if (lane == 0) tmpMn[wv] = v;
  __syncthreads();
  if (threadIdx.x == 0) {
    int nw = (blockDim.x + 63) >> 6;
    double s = tmpMn[0];
    for (int i = 1; i < nw; i++) s = fmin(s, tmpMn[i]);
    tmpMn[0] = s;
  }
  __syncthreads();
  double r = tmpMn[0];
  __syncthreads();
  return r;
}

__device__ __forceinline__ double blockReduceMaxD(double v) {
  __shared__ double tmpMx[8];
  int lane = threadIdx.x & 63, wv = threadIdx.x >> 6;
  #pragma unroll
  for (int o = 32; o > 0; o >>= 1) v = fmax(v, __shfl_down(v, o));
  if (lane == 0) tmpMx[wv] = v;
  __syncthreads();
  if (threadIdx.x == 0) {
    int nw = (blockDim.x + 63) >> 6;
    double s = tmpMx[0];
    for (int i = 1; i < nw; i++) s = fmax(s, tmpMx[i]);
    tmpMx[0] = s;
  }
  __syncthreads();
  double r = tmpMx[0];
  __syncthreads();
  return r;
}

// ---------------- small chain (fp64 for argsort stability) ----------------

__global__ void k_rnormp(const float* __restrict__ feats, double* __restrict__ ps) {
  int t = blockIdx.x * 256 + threadIdx.x;
  if (t >= KN * KHW) return;
  int ci = blockIdx.y;
  int n = t / KHW, k = t % KHW;
  const float* p = feats + (size_t)n * KC * KHW + (size_t)ci * 128 * KHW + k;
  double s = 0.0;
  for (int c = 0; c < 128; ++c) { double v = p[(size_t)c * KHW]; s += v * v; }
  ps[(size_t)ci * KN * KHW + t] = s;
}

__global__ void k_rnormc(const double* __restrict__ ps, double* __restrict__ rnorm) {
  int t = blockIdx.x * 256 + threadIdx.x;
  if (t >= KN * KHW) return;
  double s = ps[t] + ps[KN * KHW + t] + ps[2 * KN * KHW + t] + ps[3 * KN * KHW + t];
  double nn = sqrt(s);
  if (nn < 1e-12) nn = 1e-12;
  rnorm[t] = 1.0 / nn;
}

// NFT[n,k,c] = bf16(feats[n,c,k] * rnorm[n,k]); also emits SIV pre-partials
__global__ void k_nft(const float* __restrict__ feats, const double* __restrict__ rnorm,
                      const float* __restrict__ sism, bf16* __restrict__ NFT,
                      double* __restrict__ vpp) {
  __shared__ float T[32][33];
  int n = blockIdx.z, k0 = blockIdx.x * 32, c0 = blockIdx.y * 32;
  int tx = threadIdx.x, ty = threadIdx.y;
  const float* fb = feats + ((size_t)n * KC + c0) * KHW + k0;
  #pragma unroll
  for (int ii = 0; ii < 4; ii++) {
    int cl = ty * 4 + ii;
    T[cl][tx] = fb[(size_t)cl * KHW + tx];
  }
  __syncthreads();
  bf16* ob = NFT + ((size_t)n * KHW + k0) * KC + c0;
  #pragma unroll
  for (int ii = 0; ii < 4; ii++) {
    int kl = ty * 4 + ii;
    float r = (float)rnorm[n * KHW + k0 + kl];
    ob[(size_t)kl * KC + tx] = __float2bfloat16(T[tx][kl] * r);
  }
  double rs = rnorm[n * KHW + k0 + tx] * (double)sism[n * KHW + k0 + tx];
  #pragma unroll
  for (int ii = 0; ii < 4; ii++) {
    int cl = ty * 4 + ii;
    double v = (double)T[cl][tx] * rs;
    #pragma unroll
    for (int o = 16; o > 0; o >>= 1) v += __shfl_down(v, o, 32);
    if (tx == 0) vpp[((size_t)n * KC + c0 + cl) * 50 + k0 / 32] = v;
  }
}

__global__ void k_sivnorm2(const double* __restrict__ vpp, double* __restrict__ SIV) {
  int n = blockIdx.x, c = threadIdx.x;   // 512 threads
  const double* p = vpp + ((size_t)n * KC + c) * 50;
  double acc = 0;
  #pragma unroll 5
  for (int j = 0; j < 50; j++) acc += p[j];
  acc /= (double)KHW;
  double s2 = blockReduceSumD(acc * acc);
  double nn = sqrt(s2);
  if (nn < 1e-12) nn = 1e-12;
  SIV[n * KC + c] = acc / nn;
}

__global__ void k_cmP(const float* __restrict__ feats, const double* __restrict__ SIV,
                      double* __restrict__ cmp) {
  __shared__ double sv[KN][64];
  int kc = blockIdx.x, ci = blockIdx.y, n = blockIdx.z;
  for (int t = threadIdx.x; t < KN * 64; t += 256) {
    int m = t / 64, c = t % 64;
    sv[m][c] = SIV[m * KC + ci * 64 + c];
  }
  __syncthreads();
  int k = kc * 256 + threadIdx.x;
  if (k >= KHW) return;
  const float* f = feats + ((size_t)n * KC + ci * 64) * KHW + k;
  double acc[KN];
  #pragma unroll
  for (int m = 0; m < KN; m++) acc[m] = 0.0;
  for (int c = 0; c < 64; ++c) {
    double fv = f[(size_t)c * KHW];
    #pragma unroll
    for (int m = 0; m < KN; m++) acc[m] += fv * sv[m][c];
  }
  const size_t str = (size_t)KN * KN * KHW;
  #pragma unroll
  for (int m = 0; m < KN; m++)
    cmp[(size_t)ci * str + ((size_t)n * KN + m) * KHW + k] = acc[m];
}

__global__ void k_cmB(const double* __restrict__ cmp, const double* __restrict__ rnorm,
                      double* __restrict__ cm) {
  size_t t = (size_t)blockIdx.x * 256 + threadIdx.x;
  if (t >= (size_t)KN * KN * KHW) return;
  int k = t % KHW;
  int n = (int)(t / ((size_t)KN * KHW));
  const size_t str = (size_t)KN * KN * KHW;
  double s = 0;
  #pragma unroll
  for (int ci = 0; ci < 8; ci++) s += cmp[ci * str + t];
  cm[t] = s * rnorm[n * KHW + k];
}

__global__ void k_cmnorm(double* __restrict__ cm) {
  double* row = cm + (size_t)blockIdx.x * KHW;
  double s = 0;
  for (int k = threadIdx.x; k < KHW; k += 256) { double v = row[k]; s += v * v; }
  s = blockReduceSumD(s);
  double nn = sqrt(s);
  if (nn < 1e-12) nn = 1e-12;
  double rn = 1.0 / nn;
  for (int k = threadIdx.x; k < KHW; k += 256) row[k] *= rn;
}

__global__ void k_st(const double* __restrict__ cm, double* __restrict__ tbuf) {
  int b = blockIdx.x;
  int n = b / KN, m = b % KN;
  const double* base = cm + (size_t)n * KN * KHW;
  double acc = 0;
  for (int k = threadIdx.x; k < KHW; k += 256) {
    double S = 0;
    #pragma unroll
    for (int mm = 0; mm < KN; mm++) S += base[(size_t)mm * KHW + k];
    acc += base[(size_t)m * KHW + k] * S;
  }
  acc = blockReduceSumD(acc);
  if (threadIdx.x == 0) tbuf[b] = acc;
}

__global__ void k_csa(const double* __restrict__ cm, const double* __restrict__ tbuf,
                      double* __restrict__ CSAd, float* __restrict__ CSAf) {
  __shared__ double w[KN];
  int n = blockIdx.x, tid = threadIdx.x;
  if (tid == 0) {
    double v[KN], mx = -1e300;
    #pragma unroll
    for (int m = 0; m < KN; m++) { v[m] = tbuf[n * KN + m]; mx = fmax(mx, v[m]); }
    double s = 0;
    #pragma unroll
    for (int m = 0; m < KN; m++) { v[m] = exp(v[m] - mx); s += v[m]; }
    #pragma unroll
    for (int m = 0; m < KN; m++) w[m] = v[m] / s;
  }
  __syncthreads();
  double v[7];
  int cnt = 0;
  double lmin = 1e300, lmax = -1e300;
  for (int k = tid; k < KHW; k += 256) {
    double a = 0;
    #pragma unroll
    for (int m = 0; m < KN; m++) a += cm[((size_t)n * KN + m) * KHW + k] * w[m];
    v[cnt++] = a;
    lmin = fmin(lmin, a);
    lmax = fmax(lmax, a);
  }
  double mn = blockReduceMinD(lmin);
  double mx = blockReduceMaxD(lmax);
  double inv = 1.0 / (mx - mn + 1e-12);
  cnt = 0;
  for (int k = tid; k < KHW; k += 256) {
    double nv = (v[cnt++] - mn) * inv;
    CSAd[(size_t)n * KHW + k] = nv;
    CSAf[(size_t)n * KHW + k] = (float)nv;
  }
}

// rank-based stable descending argsort: idx[rank[i]] = i
// wave-parallel: 1000 blocks; block = 16 i's (4 waves x 4), lanes cover j.
__global__ void k_rank(const double* __restrict__ CSAd, int* __restrict__ idx) {
  __shared__ double key[KHW];
  int b = blockIdx.x;
  int n = b / 100, it = b % 100;
  const double* src = CSAd + (size_t)n * KHW;
  for (int j = threadIdx.x; j < KHW; j += 256) key[j] = src[j];
  __syncthreads();
  int wave = threadIdx.x >> 6, lane = threadIdx.x & 63;
  int i0 = it * 16 + wave * 4;
  double ki[4];
  #pragma unroll
  for (int ii = 0; ii < 4; ii++) ki[ii] = key[i0 + ii];
  int r[4] = {0, 0, 0, 0};
  #pragma unroll
  for (int q = 0; q < 25; q++) {
    int j = q * 64 + lane;
    double kj = key[j];
    #pragma unroll
    for (int ii = 0; ii < 4; ii++) {
      int i = i0 + ii;
      r[ii] += (kj > ki[ii]) || (kj == ki[ii] && j < i);
    }
  }
  #pragma unroll
  for (int ii = 0; ii < 4; ii++) {
    int v = r[ii];
    #pragma unroll
    for (int o = 32; o > 0; o >>= 1) v += __shfl_down(v, o);
    if (lane == 0) idx[n * KHW + v] = i0 + ii;
  }
}

// ---------------- stacked weights (n-independent): w1s[(tau,o)][i] ----------------
__global__ void k_prepw1s(const float* __restrict__ w1, const float* __restrict__ wsc,
                          bf16* __restrict__ w1s) {
  int t = blockIdx.x * 256 + threadIdx.x;   // over KM*KHW
  int m = t / KHW, i = t % KHW;
  int tau = m >> 7, o = m & 127;
  float v = (tau < 9) ? w1[((size_t)o * KHW + i) * 9 + tau]
                      : wsc[(size_t)o * KHW + i];
  w1s[t] = __float2bfloat16(v);
}

__global__ void k_prepw2(const float* __restrict__ w2, bf16* __restrict__ w2p) {
  int t = blockIdx.x * 256 + threadIdx.x;
  if (t >= KOC * 9 * KOC) return;
  int o = t / (9 * KOC), r = t % (9 * KOC);
  int s = r / KOC, i = r % KOC;
  w2p[t] = __float2bfloat16(w2[(size_t)o * 9 * KOC + (size_t)i * 9 + s]);
}

// ---------------- NF column gather: NFcg[n][c][i] = NFT[n][idx[i]][c] ----------------
__global__ void k_gath2(const short* __restrict__ NFT, const int* __restrict__ idx,
                        short* __restrict__ NFcg) {
  __shared__ short T[32][33];
  int i0 = blockIdx.x * 32, c0 = blockIdx.y * 32, n = blockIdx.z;
  int tx = threadIdx.x, ty = threadIdx.y;
  #pragma unroll
  for (int ii = 0; ii < 4; ii++) {
    int row = ty * 4 + ii;
    int id = idx[n * KHW + i0 + row];
    T[row][tx] = NFT[((size_t)n * KHW + id) * KC + c0 + tx];
  }
  __syncthreads();
  #pragma unroll
  for (int ii = 0; ii < 4; ii++) {
    int cl = ty * 4 + ii;
    NFcg[((size_t)n * KC + c0 + cl) * KHW + i0 + tx] = T[tx][cl];
  }
}

// Zpad[n, y+1, x+1, c] = bf16(NFT[n,p,c] * CSA[n,p])
__global__ void k_zprep(const bf16* __restrict__ NFT, const float* __restrict__ CSAf,
                        bf16* __restrict__ Zpad) {
  int t = blockIdx.x * 256 + threadIdx.x;   // over KN*KHW*KC/4
  const int per_n = KHW * (KC / 4);
  int n = t / per_n, r = t % per_n;
  int p = r / (KC / 4), cq = r % (KC / 4);
  float cs = CSAf[n * KHW + p];
  const short* src = (const short*)(NFT + ((size_t)n * KHW + p) * KC) + cq * 4;
  short4v v = *(const short4v*)src;
  short4v o;
  #pragma unroll
  for (int j = 0; j < 4; j++) {
    short s = v[j];
    bf16 hb = *reinterpret_cast<bf16*>(&s);
    bf16 res = __float2bfloat16(__bfloat162float(hb) * cs);
    o[j] = *reinterpret_cast<short*>(&res);
  }
  int y = p / KH, x = p % KH;
  short* dst = (short*)(Zpad + ((size_t)n * KPW * KPW + (size_t)(y + 1) * KPW + (x + 1)) * KC) + cq * 4;
  *(short4v*)dst = o;
}

// ---------------- GEMM1: U = w1s x NFcg; pipelined BK=64 template, XCD-swizzled ----------------
// 800 blocks. Tile: M=64 (w1s rows), N=128 (c), K=1600 (25 steps of 64).
// Double-buffered LDS via global_load_lds, pre-swizzled source (T2), counted vmcnt (T4).
__global__ __launch_bounds__(256) void k_gemmU(const short* __restrict__ w1s,
                                               const short* __restrict__ NFcg,
                                               bf16* __restrict__ Uc,
                                               bf16* __restrict__ Usc) {
  __shared__ __align__(16) short smem[24576];  // As[2][4096] | Bs[2][8192] (48 KB); reused as Cs[64][136]
  short* As = smem;                            // buf stride 4096 shorts (8 KB)
  short* Bs = smem + 8192;                     // buf stride 8192 shorts (16 KB)
  short* Cs = smem;
  int b = blockIdx.x;
  int workid = (b & 7) * 100 + (b >> 3);       // bijective, 800 % 8 == 0
  int pair = workid / 20;                      // 0..39 : (n, c0 tile)
  int th = workid % 20;                        // 0..19 : (tau, half)
  int n = pair >> 2, c0 = (pair & 3) * 128;
  int tau = th >> 1, half = th & 1;
  int m0 = tau * 128 + half * 64;
  int tid = threadIdx.x, lane = tid & 63, wave = tid >> 6;
  int quad = lane >> 4, l15 = lane & 15;
  int wm = (wave & 1) * 32, wn = (wave >> 1) * 64;
  int sk = ((tid & 7) ^ ((tid >> 3) & 7)) * 8; // pre-swizzled 16B-chunk (shorts)
  int rowg = tid >> 3;                          // 0..31
  const short* Bb = NFcg + (size_t)n * KC * KHW;
  const short* pA[2];
  #pragma unroll
  for (int g = 0; g < 2; g++)
    pA[g] = w1s + (size_t)(m0 + g * 32 + rowg) * KHW + sk;
  const short* pB[4];
  #pragma unroll
  for (int g = 0; g < 4; g++)
    pB[g] = Bb + (size_t)(c0 + g * 32 + rowg) * KHW + sk;
  char* lA = (char*)As + tid * 16;
  char* lB = (char*)Bs + tid * 16;
  int bq = (l15 >> 2) & 1;
  int qx = (quad ^ (l15 & 3)) * 8;
  int koff0 = 32 * bq + qx;
  int koff1 = 32 * (1 - bq) + qx;
  f32x4 acc[2][4] = {};
  // prologue: stage step 0 into buf 0
  gload16(pA[0], lA); gload16(pA[1], lA + 4096);
  gload16(pB[0], lB); gload16(pB[1], lB + 4096);
  gload16(pB[2], lB + 8192); gload16(pB[3], lB + 12288);
  const int NS = 25;
  for (int s = 0; s < NS; s++) {
    int cb = s & 1, nb = cb ^ 1;
    if (s + 1 < NS) {
      int off = (s + 1) * 64;
      char* la = lA + nb * 8192;               // As buf stride in bytes
      char* lb = lB + nb * 16384;              // Bs buf stride in bytes
      gload16(pA[0] + off, la); gload16(pA[1] + off, la + 4096);
      gload16(pB[0] + off, lb); gload16(pB[1] + off, lb + 4096);
      gload16(pB[2] + off, lb + 8192); gload16(pB[3] + off, lb + 12288);
      asm volatile("s_waitcnt vmcnt(6)" ::: "memory");   // current buf's 6 done; next 6 in flight
    } else {
      asm volatile("s_waitcnt vmcnt(0)" ::: "memory");
    }
    __builtin_amdgcn_s_barrier();
    __builtin_amdgcn_sched_barrier(0);
    const short* Ab = As + cb * 4096;
    const short* Bbf = Bs + cb * 8192;
    #pragma unroll
    for (int ks = 0; ks < 2; ks++) {
      int ko = (ks == 0) ? koff0 : koff1;
      short8 av[2], bv[4];
      #pragma unroll
      for (int t = 0; t < 2; t++) av[t] = *(const short8*)&Ab[(wm + t * 16 + l15) * 64 + ko];
      #pragma unroll
      for (int t = 0; t < 4; t++) bv[t] = *(const short8*)&Bbf[(wn + t * 16 + l15) * 64 + ko];
      #pragma unroll
      for (int ti = 0; ti < 2; ti++)
        #pragma unroll
        for (int tj = 0; tj < 4; tj++)
          acc[ti][tj] = __builtin_amdgcn_mfma_f32_16x16x32_bf16(av[ti], bv[tj], acc[ti][tj], 0, 0, 0);
    }
    __builtin_amdgcn_s_barrier();              // all reads consumed; safe to overwrite cb
  }
  // epilogue: bf16 transpose via Cs, then coalesced store
  #pragma unroll
  for (int ti = 0; ti < 2; ti++) {
    int lr = wm + ti * 16 + quad * 4;
    #pragma unroll
    for (int tj = 0; tj < 4; tj++) {
      int lc = wn + tj * 16 + l15;
      #pragma unroll
      for (int r = 0; r < 4; r++)
        *(bf16*)&Cs[(lr + r) * 136 + lc] = __float2bfloat16(acc[ti][tj][r]);
    }
  }
  __syncthreads();
  int dyq = tau / 3, dxq = tau % 3;
  #pragma unroll
  for (int pass = 0; pass < 4; pass++) {
    int row = pass * 16 + (tid >> 4);          // 0..63
    int col = (tid & 15) * 8;                  // 0..127
    if (tau < 9) {
      *(float4*)&Uc[((size_t)((n * 3 + dyq) * 128 + half * 64 + row)) * 1536 + dxq * 512 + c0 + col] =
          *(const float4*)&Cs[row * 136 + col];
    } else {
      *(float4*)&Usc[((size_t)(n * 128 + half * 64 + row)) * 512 + c0 + col] =
          *(const float4*)&Cs[row * 136 + col];
    }
  }
}

// ---------------- convh: dy-split pipelined GEMM, M=128(o) x N=64(p), K=1536 (conv) / 512 (sc)
__global__ __launch_bounds__(256) void k_convh(const short* __restrict__ Uc,
                                               const short* __restrict__ Usc,
                                               const short* __restrict__ Zpad,
                                               float* __restrict__ Hpart) {
  __shared__ __align__(16) short smem[24576];  // As[2][8192] | Bs[2][4096]  (48 KB)
  short* As = smem;
  short* Bs = smem + 16384;
  int b = blockIdx.x;
  int wgid = (b & 7) * 125 + (b >> 3);         // bijective, 1000 % 8 == 0
  int n = wgid / 100, rest = wgid % 100;
  int dy = rest / 25, pt = rest % 25;
  int p0 = pt * 64;
  int tid = threadIdx.x, lane = tid & 63, wave = tid >> 6;
  int quad = lane >> 4, l15 = lane & 15;
  int wm = (wave & 1) * 64, wn = (wave >> 1) * 32;
  // staging: pre-swizzled global source; LDS stays linear (rule #21)
  int sk = ((tid & 7) ^ ((tid >> 3) & 7)) * 8;   // swizzled 16B-chunk (shorts)
  int rowg = tid >> 3;                            // 0..31
  bool isconv = (dy < 3);
  const short* Zb = Zpad + (size_t)n * KPW * KPW * KC;
  const short* Abase = isconv ? Uc + ((size_t)((n * 3 + dy) * 128)) * 1536
                              : Usc + ((size_t)(n * 128)) * 512;
  int astr = isconv ? 1536 : 512;
  const short* pA[4];
  #pragma unroll
  for (int g = 0; g < 4; g++)
    pA[g] = Abase + (size_t)(g * 32 + rowg) * astr + sk;
  const short* pB[2];
  #pragma unroll
  for (int g = 0; g < 2; g++) {
    int p = p0 + g * 32 + rowg;
    int y = p / KH, x = p % KH;
    int yy = isconv ? (y + dy) : (y + 1);
    int xx = isconv ? x : (x + 1);
    pB[g] = Zb + ((size_t)yy * KPW + xx) * KC + sk;
  }
  char* lA = (char*)As + tid * 16;
  char* lB = (char*)Bs + tid * 16;
  int NS = isconv ? 24 : 8;
  // swizzled ds_read k offsets (shorts)
  int bq = (l15 >> 2) & 1;
  int qx = (quad ^ (l15 & 3)) * 8;
  int koff0 = 32 * bq + qx;
  int koff1 = 32 * (1 - bq) + qx;
  f32x4 acc[4][2] = {};
  // prologue: stage step 0 into buf 0
  gload16(pA[0], lA); gload16(pA[1], lA + 4096);
  gload16(pA[2], lA + 8192); gload16(pA[3], lA + 12288);
  gload16(pB[0], lB); gload16(pB[1], lB + 4096);
  for (int s = 0; s < NS; s++) {
    int cb = s & 1, nb = cb ^ 1;
    if (s + 1 < NS) {
      int off = (s + 1) * 64;
      char* la = lA + nb * 16384;
      char* lb = lB + nb * 8192;
      gload16(pA[0] + off, la); gload16(pA[1] + off, la + 4096);
      gload16(pA[2] + off, la + 8192); gload16(pA[3] + off, la + 12288);
      gload16(pB[0] + off, lb); gload16(pB[1] + off, lb + 4096);
      asm volatile("s_waitcnt vmcnt(6)" ::: "memory");   // current buf done; next 6 in flight
    } else {
      asm volatile("s_waitcnt vmcnt(0)" ::: "memory");
    }
    __builtin_amdgcn_s_barrier();
    __builtin_amdgcn_sched_barrier(0);
    const short* Ab = As + cb * 8192;
    const short* Bb = Bs + cb * 4096;
    #pragma unroll
    for (int ks = 0; ks < 2; ks++) {
      int ko = (ks == 0) ? koff0 : koff1;
      short8 av[4], bv[2];
      #pragma unroll
      for (int t = 0; t < 4; t++) av[t] = *(const short8*)&Ab[(wm + t * 16 + l15) * 64 + ko];
      #pragma unroll
      for (int t = 0; t < 2; t++) bv[t] = *(const short8*)&Bb[(wn + t * 16 + l15) * 64 + ko];
      #pragma unroll
      for (int ti = 0; ti < 4; ti++)
        #pragma unroll
        for (int tj = 0; tj < 2; tj++)
          acc[ti][tj] = __builtin_amdgcn_mfma_f32_16x16x32_bf16(av[ti], bv[tj], acc[ti][tj], 0, 0, 0);
    }
    __builtin_amdgcn_s_barrier();              // lgkm drained before MFMA; safe to overwrite cb
  }
  float* cbp = Hpart + ((size_t)(dy * KN + n)) * KOC * KHW;
  #pragma unroll
  for (int ti = 0; ti < 4; ti++) {
    int o = wm + ti * 16 + quad * 4;
    #pragma unroll
    for (int tj = 0; tj < 2; tj++) {
      int q = p0 + wn + tj * 16 + l15;
      #pragma unroll
      for (int r = 0; r < 4; r++)
        cbp[(size_t)(o + r) * KHW + q] = acc[ti][tj][r];
    }
  }
}

// hpadT[n, y+1, x+1, o] = bf16(relu(b1[o] + Hpart[0]+Hpart[1]+Hpart[2]))
__global__ void k_hprep3(const float* __restrict__ Hpart, const float* __restrict__ b1,
                         bf16* __restrict__ hpadT) {
  __shared__ float T[32][132];
  int n = blockIdx.y, p0 = blockIdx.x * 32;
  int tx = threadIdx.x, ty = threadIdx.y;
  const size_t str = (size_t)KN * KOC * KHW;
  const float* hb = Hpart + (size_t)n * KOC * KHW;
  #pragma unroll
  for (int oc = 0; oc < 16; oc++) {
    int o = oc * 8 + ty;
    size_t off = (size_t)o * KHW + p0 + tx;
    T[tx][o] = fmaxf(hb[off] + hb[str + off] + hb[2 * str + off] + b1[o], 0.0f);
  }
  __syncthreads();
  bf16* hp = hpadT + (size_t)n * KPW * KPW * KOC;
  #pragma unroll
  for (int pc = 0; pc < 4; pc++) {
    int pl = ty * 4 + pc;
    int pp = p0 + pl;
    int yy = pp / KH, xx = pp % KH;
    bf16* row = hp + ((size_t)(yy + 1) * KPW + (xx + 1)) * KOC;
    #pragma unroll
    for (int u = 0; u < 4; u++) row[tx * 4 + u] = __float2bfloat16(T[pl][tx * 4 + u]);
  }
}

// ---------------- conv2 (3x3, 128->128): same pipelined template, K=384 per dy ----------------
// 750 blocks = 10n * 3dy * 25pt, bijective XCD swizzle (750 = 8*93+6).
__global__ __launch_bounds__(256) void k_conv2(const short* __restrict__ w2p,
                                               const short* __restrict__ hpadT,
                                               float* __restrict__ Cpart) {
  __shared__ __align__(16) short smem[24576];
  short* As = smem;
  short* Bs = smem + 16384;
  int b = blockIdx.x;
  int xcd = b & 7, bi = b >> 3;
  int wgid = (xcd < 6 ? xcd * 94 : 6 * 94 + (xcd - 6) * 93) + bi;
  int n = wgid / 75, rest = wgid % 75;
  int dy = rest / 25, pt = rest % 25;
  int p0 = pt * 64;
  int tid = threadIdx.x, lane = tid & 63, wave = tid >> 6;
  int quad = lane >> 4, l15 = lane & 15;
  int wm = (wave & 1) * 64, wn = (wave >> 1) * 32;
  int sk = ((tid & 7) ^ ((tid >> 3) & 7)) * 8;
  int rowg = tid >> 3;
  const short* hb = hpadT + (size_t)n * KPW * KPW * KOC;
  const short* pA[4];
  #pragma unroll
  for (int g = 0; g < 4; g++)
    pA[g] = w2p + (size_t)(g * 32 + rowg) * (9 * KOC) + dy * 384 + sk;
  const short* pB[2];
  #pragma unroll
  for (int g = 0; g < 2; g++) {
    int p = p0 + g * 32 + rowg;
    int y = p / KH, x = p % KH;
    pB[g] = hb + ((size_t)(y + dy) * KPW + x) * KOC + sk;   // k = dx*128+c contiguous
  }
  char* lA = (char*)As + tid * 16;
  char* lB = (char*)Bs + tid * 16;
  const int NS = 6;                            // K = 384 = 6 * 64
  int bq = (l15 >> 2) & 1;
  int qx = (quad ^ (l15 & 3)) * 8;
  int koff0 = 32 * bq + qx;
  int koff1 = 32 * (1 - bq) + qx;
  f32x4 acc[4][2] = {};
  gload16(pA[0], lA); gload16(pA[1], lA + 4096);
  gload16(pA[2], lA + 8192); gload16(pA[3], lA + 12288);
  gload16(pB[0], lB); gload16(pB[1], lB + 4096);
  for (int s = 0; s < NS; s++) {
    int cb = s & 1, nb = cb ^ 1;
    if (s + 1 < NS) {
      int off = (s + 1) * 64;
      char* la = lA + nb * 16384;
      char* lb = lB + nb * 8192;
      gload16(pA[0] + off, la); gload16(pA[1] + off, la + 4096);
      gload16(pA[2] + off, la + 8192); gload16(pA[3] + off, la + 12288);
      gload16(pB[0] + off, lb); gload16(pB[1] + off, lb + 4096);
      asm volatile("s_waitcnt vmcnt(6)" ::: "memory");
    } else {
      asm volatile("s_waitcnt vmcnt(0)" ::: "memory");
    }
    __builtin_amdgcn_s_barrier();
    __builtin_amdgcn_sched_barrier(0);
    const short* Ab = As + cb * 8192;
    const short* Bb = Bs + cb * 4096;
    #pragma unroll
    for (int ks = 0; ks < 2; ks++) {
      int ko = (ks == 0) ? koff0 : koff1;
      short8 av[4], bv[2];
      #pragma unroll
      for (int t = 0; t < 4; t++) av[t] = *(const short8*)&Ab[(wm + t * 16 + l15) * 64 + ko];
      #pragma unroll
      for (int t = 0; t < 2; t++) bv[t] = *(const short8*)&Bb[(wn + t * 16 + l15) * 64 + ko];
      #pragma unroll
      for (int ti = 0; ti < 4; ti++)
        #pragma unroll
        for (int tj = 0; tj < 2; tj++)
          acc[ti][tj] = __builtin_amdgcn_mfma_f32_16x16x32_bf16(av[ti], bv[tj], acc[ti][tj], 0, 0, 0);
    }
    __builtin_amdgcn_s_barrier();
  }
  float* cbp = Cpart + ((size_t)(dy * KN + n)) * KOC * KHW;
  #pragma unroll
  for (int ti = 0; ti < 4; ti++) {
    int o = wm + ti * 16 + quad * 4;
    #pragma unroll
    for (int tj = 0; tj < 2; tj++) {
      int q = p0 + wn + tj * 16 + l15;
      #pragma unroll
      for (int r = 0; r < 4; r++)
        cbp[(size_t)(o + r) * KHW + q] = acc[ti][tj][r];
    }
  }
}

// out = relu(sum_dy Cpart + b2 + shortcut(Hpart[3]) + bs)
__global__ void k_final2(const float* __restrict__ Cpart, const float* __restrict__ Hpart,
                         const float* __restrict__ b2, const float* __restrict__ bs,
                         float* __restrict__ out) {
  int t = blockIdx.x * 256 + threadIdx.x;
  if (t >= KN * KOC * KHW) return;
  int o = (t / KHW) % KOC;
  const size_t stride = (size_t)KN * KOC * KHW;
  float v = Cpart[t] + Cpart[stride + t] + Cpart[2 * stride + t] +
            Hpart[3 * stride + t] + b2[o] + bs[o];
  out[t] = fmaxf(v, 0.0f);
}

// ---------------- launch ----------------
extern "C" void kernel_launch(void* const* d_in, const int* in_sizes, int n_in,
                              void* d_out, int out_size, void* d_ws, size_t ws_size,
                              hipStream_t stream) {
  const float* feats = (const float*)d_in[0];
  const float* sisms = (const float*)d_in[1];
  const float* w1 = (const float*)d_in[2];
  const float* b1 = (const float*)d_in[3];
  const float* w2 = (const float*)d_in[4];
  const float* b2 = (const float*)d_in[5];
  const float* wsc = (const float*)d_in[6];
  const float* bsc = (const float*)d_in[7];
  float* out = (float*)d_out;

  char* w = (char*)d_ws;
  auto carve = [&](size_t bytes) -> void* {
    void* p = (void*)w;
    w += (bytes + 255) & ~(size_t)255;
    return p;
  };
  bf16* NFT   = (bf16*)carve((size_t)KN * KHW * KC * 2);          // 16.4 MB
  bf16* NFcg  = (bf16*)carve((size_t)KN * KC * KHW * 2);          // 16.4 MB
  bf16* Uc    = (bf16*)carve((size_t)KN * 3 * 128 * 1536 * 2);    // 11.8 MB
  bf16* Usc   = (bf16*)carve((size_t)KN * 128 * 512 * 2);         // 1.3 MB
  bf16* w1s   = (bf16*)carve((size_t)KM * KHW * 2);               // 4.1 MB
  bf16* Zpad  = (bf16*)carve((size_t)KN * KPW * KPW * KC * 2);    // 18.1 MB
  bf16* hpadT = (bf16*)carve((size_t)KN * KPW * KPW * KOC * 2);   // 4.5 MB
  float* Hpart = (float*)carve((size_t)4 * KN * KOC * KHW * 4);   // 32.8 MB
  float* Cpart = (float*)carve((size_t)3 * KN * KOC * KHW * 4);   // 24.6 MB
  bf16* w2p   = (bf16*)carve((size_t)KOC * 9 * KOC * 2);
  double* psbuf = (double*)carve((size_t)4 * KN * KHW * 8);
  double* rnorm = (double*)carve((size_t)KN * KHW * 8);
  double* vpp   = (double*)carve((size_t)KN * KC * 50 * 8);       // 2.05 MB
  double* SIV   = (double*)carve((size_t)KN * KC * 8);
  double* cmp   = (double*)carve((size_t)8 * KN * KN * KHW * 8);  // 10.2 MB
  double* cm    = (double*)carve((size_t)KN * KN * KHW * 8);
  double* tbuf  = (double*)carve((size_t)KN * KN * 8);
  double* CSAd  = (double*)carve((size_t)KN * KHW * 8);
  float* CSAf   = (float*)carve((size_t)KN * KHW * 4);
  int* idxb     = (int*)carve((size_t)KN * KHW * 4);

  hipMemsetAsync(hpadT, 0, (size_t)KN * KPW * KPW * KOC * 2, stream);
  hipMemsetAsync(Zpad, 0, (size_t)KN * KPW * KPW * KC * 2, stream);

  k_rnormp<<<dim3(63, 4), 256, 0, stream>>>(feats, psbuf);
  k_rnormc<<<63, 256, 0, stream>>>(psbuf, rnorm);
  k_nft<<<dim3(50, 16, KN), dim3(32, 8), 0, stream>>>(feats, rnorm, sisms, NFT, vpp);
  k_sivnorm2<<<KN, 512, 0, stream>>>(vpp, SIV);
  k_cmP<<<dim3(7, 8, KN), 256, 0, stream>>>(feats, SIV, cmp);
  k_cmB<<<625, 256, 0, stream>>>(cmp, rnorm, cm);
  k_cmnorm<<<KN * KN, 256, 0, stream>>>(cm);
  k_st<<<KN * KN, 256, 0, stream>>>(cm, tbuf);
  k_csa<<<KN, 256, 0, stream>>>(cm, tbuf, CSAd, CSAf);
  k_rank<<<1000, 256, 0, stream>>>(CSAd, idxb);

  k_prepw1s<<<KM * KHW / 256, 256, 0, stream>>>(w1, wsc, w1s);
  k_prepw2<<<576, 256, 0, stream>>>(w2, w2p);
  k_gath2<<<dim3(50, 16, KN), dim3(32, 8), 0, stream>>>((const short*)NFT, idxb, (short*)NFcg);
  k_zprep<<<KN * KHW * (KC / 4) / 256, 256, 0, stream>>>(NFT, CSAf, Zpad);

  k_gemmU<<<800, 256, 0, stream>>>((const short*)w1s, (const short*)NFcg, Uc, Usc);
  k_convh<<<1000, 256, 0, stream>>>((const short*)Uc, (const short*)Usc,
                                    (const short*)Zpad, Hpart);
  k_hprep3<<<dim3(50, KN), dim3(32, 8), 0, stream>>>(Hpart, b1, hpadT);
  k_conv2<<<750, 256, 0, stream>>>((const short*)w2p, (const short*)hpadT, Cpart);
  k_final2<<<8000, 256, 0, stream>>>(Cpart, Hpart, b2, bsc, out);
}

// Round 6
// 284.067 us; speedup vs baseline: 1.0612x; 1.0052x over previous
//
#include <hip/hip_runtime.h>
#include <hip/hip_bf16.h>
#include <math.h>

typedef short short8 __attribute__((ext_vector_type(8)));
typedef short short4v __attribute__((ext_vector_type(4)));
typedef float f32x4 __attribute__((ext_vector_type(4)));
typedef __hip_bfloat16 bf16;

// problem constants
#define KN 10
#define KC 512
#define KHW 1600
#define KH 40
#define KOC 128
#define KPW 42   // padded spatial (40+2)
#define KM 1280  // stacked M: 9 conv taps * 128 + 128 shortcut

// direct global->LDS DMA, 16B per lane. LDS dest must be wave-uniform base + lane*16.
__device__ __forceinline__ void gload16(const void* g, void* l) {
  __builtin_amdgcn_global_load_lds(
      (const __attribute__((address_space(1))) unsigned int*)g,
      (__attribute__((address_space(3))) unsigned int*)l, 16, 0, 0);
}

// ---------------- block reduction helpers (fp64) ----------------
__device__ __forceinline__ double blockReduceSumD(double v) {
  __shared__ double tmpS[8];
  int lane = threadIdx.x & 63, wv = threadIdx.x >> 6;
  #pragma unroll
  for (int o = 32; o > 0; o >>= 1) v += __shfl_down(v, o);
  if (lane == 0) tmpS[wv] = v;
  __syncthreads();
  if (threadIdx.x == 0) {
    int nw = (blockDim.x + 63) >> 6;
    double s = 0;
    for (int i = 0; i < nw; i++) s += tmpS[i];
    tmpS[0] = s;
  }
  __syncthreads();
  double r = tmpS[0];
  __syncthreads();
  return r;
}

__device__ __forceinline__ double blockReduceMinD(double v) {
  __shared__ double tmpMn[8];
  int lane = threadIdx.x & 63, wv = threadIdx.x >> 6;
  #pragma unroll
  for (int o = 32; o > 0; o >>= 1) v = fmin(v, __shfl_down(v, o));
  if (lane == 0) tmpMn[wv] = v;
  __syncthreads();
  if (threadIdx.x == 0) {
    int nw = (blockDim.x + 63) >> 6;
    double s = tmpMn[0];
    for (int i = 1; i < nw; i++) s = fmin(s, tmpMn[i]);
    tmpMn[0] = s;
  }
  __syncthreads();
  double r = tmpMn[0];
  __syncthreads();
  return r;
}

__device__ __forceinline__ double blockReduceMaxD(double v) {
  __shared__ double tmpMx[8];
  int lane = threadIdx.x & 63, wv = threadIdx.x >> 6;
  #pragma unroll
  for (int o = 32; o > 0; o >>= 1) v = fmax(v, __shfl_down(v, o));
  if (lane == 0) tmpMx[wv] = v;
  __syncthreads();
  if (threadIdx.x == 0) {
    int nw = (blockDim.x + 63) >> 6;
    double s = tmpMx[0];
    for (int i = 1; i < nw; i++) s = fmax(s, tmpMx[i]);
    tmpMx[0] = s;
  }
  __syncthreads();
  double r = tmpMx[0];
  __syncthreads();
  return r;
}

// ---------------- small chain (fp64 for argsort stability) ----------------

__global__ void k_rnormp(const float* __restrict__ feats, double* __restrict__ ps) {
  int t = blockIdx.x * 256 + threadIdx.x;
  if (t >= KN * KHW) return;
  int ci = blockIdx.y;
  int n = t / KHW, k = t % KHW;
  const float* p = feats + (size_t)n * KC * KHW + (size_t)ci * 128 * KHW + k;
  double s = 0.0;
  for (int c = 0; c < 128; ++c) { double v = p[(size_t)c * KHW]; s += v * v; }
  ps[(size_t)ci * KN * KHW + t] = s;
}

__global__ void k_rnormc(const double* __restrict__ ps, double* __restrict__ rnorm) {
  int t = blockIdx.x * 256 + threadIdx.x;
  if (t >= KN * KHW) return;
  double s = ps[t] + ps[KN * KHW + t] + ps[2 * KN * KHW + t] + ps[3 * KN * KHW + t];
  double nn = sqrt(s);
  if (nn < 1e-12) nn = 1e-12;
  rnorm[t] = 1.0 / nn;
}

// NFT[n,k,c] = bf16(feats[n,c,k] * rnorm[n,k]); also emits SIV pre-partials
__global__ void k_nft(const float* __restrict__ feats, const double* __restrict__ rnorm,
                      const float* __restrict__ sism, bf16* __restrict__ NFT,
                      double* __restrict__ vpp) {
  __shared__ float T[32][33];
  int n = blockIdx.z, k0 = blockIdx.x * 32, c0 = blockIdx.y * 32;
  int tx = threadIdx.x, ty = threadIdx.y;
  const float* fb = feats + ((size_t)n * KC + c0) * KHW + k0;
  #pragma unroll
  for (int ii = 0; ii < 4; ii++) {
    int cl = ty * 4 + ii;
    T[cl][tx] = fb[(size_t)cl * KHW + tx];
  }
  __syncthreads();
  bf16* ob = NFT + ((size_t)n * KHW + k0) * KC + c0;
  #pragma unroll
  for (int ii = 0; ii < 4; ii++) {
    int kl = ty * 4 + ii;
    float r = (float)rnorm[n * KHW + k0 + kl];
    ob[(size_t)kl * KC + tx] = __float2bfloat16(T[tx][kl] * r);
  }
  double rs = rnorm[n * KHW + k0 + tx] * (double)sism[n * KHW + k0 + tx];
  #pragma unroll
  for (int ii = 0; ii < 4; ii++) {
    int cl = ty * 4 + ii;
    double v = (double)T[cl][tx] * rs;
    #pragma unroll
    for (int o = 16; o > 0; o >>= 1) v += __shfl_down(v, o, 32);
    if (tx == 0) vpp[((size_t)n * KC + c0 + cl) * 50 + k0 / 32] = v;
  }
}

__global__ void k_sivnorm2(const double* __restrict__ vpp, double* __restrict__ SIV) {
  int n = blockIdx.x, c = threadIdx.x;   // 512 threads
  const double* p = vpp + ((size_t)n * KC + c) * 50;
  double acc = 0;
  #pragma unroll 5
  for (int j = 0; j < 50; j++) acc += p[j];
  acc /= (double)KHW;
  double s2 = blockReduceSumD(acc * acc);
  double nn = sqrt(s2);
  if (nn < 1e-12) nn = 1e-12;
  SIV[n * KC + c] = acc / nn;
}

__global__ void k_cmP(const float* __restrict__ feats, const double* __restrict__ SIV,
                      double* __restrict__ cmp) {
  __shared__ double sv[KN][64];
  int kc = blockIdx.x, ci = blockIdx.y, n = blockIdx.z;
  for (int t = threadIdx.x; t < KN * 64; t += 256) {
    int m = t / 64, c = t % 64;
    sv[m][c] = SIV[m * KC + ci * 64 + c];
  }
  __syncthreads();
  int k = kc * 256 + threadIdx.x;
  if (k >= KHW) return;
  const float* f = feats + ((size_t)n * KC + ci * 64) * KHW + k;
  double acc[KN];
  #pragma unroll
  for (int m = 0; m < KN; m++) acc[m] = 0.0;
  for (int c = 0; c < 64; ++c) {
    double fv = f[(size_t)c * KHW];
    #pragma unroll
    for (int m = 0; m < KN; m++) acc[m] += fv * sv[m][c];
  }
  const size_t str = (size_t)KN * KN * KHW;
  #pragma unroll
  for (int m = 0; m < KN; m++)
    cmp[(size_t)ci * str + ((size_t)n * KN + m) * KHW + k] = acc[m];
}

__global__ void k_cmB(const double* __restrict__ cmp, const double* __restrict__ rnorm,
                      double* __restrict__ cm) {
  size_t t = (size_t)blockIdx.x * 256 + threadIdx.x;
  if (t >= (size_t)KN * KN * KHW) return;
  int k = t % KHW;
  int n = (int)(t / ((size_t)KN * KHW));
  const size_t str = (size_t)KN * KN * KHW;
  double s = 0;
  #pragma unroll
  for (int ci = 0; ci < 8; ci++) s += cmp[ci * str + t];
  cm[t] = s * rnorm[n * KHW + k];
}

__global__ void k_cmnorm(double* __restrict__ cm) {
  double* row = cm + (size_t)blockIdx.x * KHW;
  double s = 0;
  for (int k = threadIdx.x; k < KHW; k += 256) { double v = row[k]; s += v * v; }
  s = blockReduceSumD(s);
  double nn = sqrt(s);
  if (nn < 1e-12) nn = 1e-12;
  double rn = 1.0 / nn;
  for (int k = threadIdx.x; k < KHW; k += 256) row[k] *= rn;
}

__global__ void k_st(const double* __restrict__ cm, double* __restrict__ tbuf) {
  int b = blockIdx.x;
  int n = b / KN, m = b % KN;
  const double* base = cm + (size_t)n * KN * KHW;
  double acc = 0;
  for (int k = threadIdx.x; k < KHW; k += 256) {
    double S = 0;
    #pragma unroll
    for (int mm = 0; mm < KN; mm++) S += base[(size_t)mm * KHW + k];
    acc += base[(size_t)m * KHW + k] * S;
  }
  acc = blockReduceSumD(acc);
  if (threadIdx.x == 0) tbuf[b] = acc;
}

__global__ void k_csa(const double* __restrict__ cm, const double* __restrict__ tbuf,
                      double* __restrict__ CSAd, float* __restrict__ CSAf) {
  __shared__ double w[KN];
  int n = blockIdx.x, tid = threadIdx.x;
  if (tid == 0) {
    double v[KN], mx = -1e300;
    #pragma unroll
    for (int m = 0; m < KN; m++) { v[m] = tbuf[n * KN + m]; mx = fmax(mx, v[m]); }
    double s = 0;
    #pragma unroll
    for (int m = 0; m < KN; m++) { v[m] = exp(v[m] - mx); s += v[m]; }
    #pragma unroll
    for (int m = 0; m < KN; m++) w[m] = v[m] / s;
  }
  __syncthreads();
  double v[7];
  int cnt = 0;
  double lmin = 1e300, lmax = -1e300;
  for (int k = tid; k < KHW; k += 256) {
    double a = 0;
    #pragma unroll
    for (int m = 0; m < KN; m++) a += cm[((size_t)n * KN + m) * KHW + k] * w[m];
    v[cnt++] = a;
    lmin = fmin(lmin, a);
    lmax = fmax(lmax, a);
  }
  double mn = blockReduceMinD(lmin);
  double mx = blockReduceMaxD(lmax);
  double inv = 1.0 / (mx - mn + 1e-12);
  cnt = 0;
  for (int k = tid; k < KHW; k += 256) {
    double nv = (v[cnt++] - mn) * inv;
    CSAd[(size_t)n * KHW + k] = nv;
    CSAf[(size_t)n * KHW + k] = (float)nv;
  }
}

// rank-based stable descending argsort: idx[rank[i]] = i
// wave-parallel: 1000 blocks; block = 16 i's (4 waves x 4), lanes cover j.
__global__ void k_rank(const double* __restrict__ CSAd, int* __restrict__ idx) {
  __shared__ double key[KHW];
  int b = blockIdx.x;
  int n = b / 100, it = b % 100;
  const double* src = CSAd + (size_t)n * KHW;
  for (int j = threadIdx.x; j < KHW; j += 256) key[j] = src[j];
  __syncthreads();
  int wave = threadIdx.x >> 6, lane = threadIdx.x & 63;
  int i0 = it * 16 + wave * 4;
  double ki[4];
  #pragma unroll
  for (int ii = 0; ii < 4; ii++) ki[ii] = key[i0 + ii];
  int r[4] = {0, 0, 0, 0};
  #pragma unroll
  for (int q = 0; q < 25; q++) {
    int j = q * 64 + lane;
    double kj = key[j];
    #pragma unroll
    for (int ii = 0; ii < 4; ii++) {
      int i = i0 + ii;
      r[ii] += (kj > ki[ii]) || (kj == ki[ii] && j < i);
    }
  }
  #pragma unroll
  for (int ii = 0; ii < 4; ii++) {
    int v = r[ii];
    #pragma unroll
    for (int o = 32; o > 0; o >>= 1) v += __shfl_down(v, o);
    if (lane == 0) idx[n * KHW + v] = i0 + ii;
  }
}

// ---------------- stacked weights (n-independent): w1s[(tau,o)][i] ----------------
__global__ void k_prepw1s(const float* __restrict__ w1, const float* __restrict__ wsc,
                          bf16* __restrict__ w1s) {
  int t = blockIdx.x * 256 + threadIdx.x;   // over KM*KHW
  int m = t / KHW, i = t % KHW;
  int tau = m >> 7, o = m & 127;
  float v = (tau < 9) ? w1[((size_t)o * KHW + i) * 9 + tau]
                      : wsc[(size_t)o * KHW + i];
  w1s[t] = __float2bfloat16(v);
}

__global__ void k_prepw2(const float* __restrict__ w2, bf16* __restrict__ w2p) {
  int t = blockIdx.x * 256 + threadIdx.x;
  if (t >= KOC * 9 * KOC) return;
  int o = t / (9 * KOC), r = t % (9 * KOC);
  int s = r / KOC, i = r % KOC;
  w2p[t] = __float2bfloat16(w2[(size_t)o * 9 * KOC + (size_t)i * 9 + s]);
}

// ---------------- zero only the padding borders of Zpad and hpadT ----------------
// interiors are fully overwritten by k_zprep / convh-epilogue+k_hprep3.
// 164 border cells per 42x42 frame; short8 stores.
__global__ void k_zborder(bf16* __restrict__ Zpad, bf16* __restrict__ hpadT) {
  int t = blockIdx.x * 256 + threadIdx.x;
  const int ZW = KN * 164 * (KC / 8);       // 104960
  const int HWm = KN * 164 * (KOC / 8);     // 26240
  int b;
  if (t < ZW) {
    int n = t / (164 * 64), r = t % (164 * 64);
    b = r / 64;
    int c8 = r % 64;
    int y, x;
    if (b < 42) { y = 0; x = b; }
    else if (b < 84) { y = 41; x = b - 42; }
    else if (b < 124) { y = b - 84 + 1; x = 0; }
    else { y = b - 124 + 1; x = 41; }
    short8 z = {};
    *(short8*)((short*)Zpad + ((size_t)n * KPW * KPW + (size_t)y * KPW + x) * KC + c8 * 8) = z;
  } else if (t < ZW + HWm) {
    int u = t - ZW;
    int n = u / (164 * 16), r = u % (164 * 16);
    b = r / 16;
    int c8 = r % 16;
    int y, x;
    if (b < 42) { y = 0; x = b; }
    else if (b < 84) { y = 41; x = b - 42; }
    else if (b < 124) { y = b - 84 + 1; x = 0; }
    else { y = b - 124 + 1; x = 41; }
    short8 z = {};
    *(short8*)((short*)hpadT + ((size_t)n * KPW * KPW + (size_t)y * KPW + x) * KOC + c8 * 8) = z;
  }
}

// ---------------- NF column gather: NFcg[n][c][i] = NFT[n][idx[i]][c] ----------------
__global__ void k_gath2(const short* __restrict__ NFT, const int* __restrict__ idx,
                        short* __restrict__ NFcg) {
  __shared__ short T[32][33];
  int i0 = blockIdx.x * 32, c0 = blockIdx.y * 32, n = blockIdx.z;
  int tx = threadIdx.x, ty = threadIdx.y;
  #pragma unroll
  for (int ii = 0; ii < 4; ii++) {
    int row = ty * 4 + ii;
    int id = idx[n * KHW + i0 + row];
    T[row][tx] = NFT[((size_t)n * KHW + id) * KC + c0 + tx];
  }
  __syncthreads();
  #pragma unroll
  for (int ii = 0; ii < 4; ii++) {
    int cl = ty * 4 + ii;
    NFcg[((size_t)n * KC + c0 + cl) * KHW + i0 + tx] = T[tx][cl];
  }
}

// Zpad[n, y+1, x+1, c] = bf16(NFT[n,p,c] * CSA[n,p])
__global__ void k_zprep(const bf16* __restrict__ NFT, const float* __restrict__ CSAf,
                        bf16* __restrict__ Zpad) {
  int t = blockIdx.x * 256 + threadIdx.x;   // over KN*KHW*KC/4
  const int per_n = KHW * (KC / 4);
  int n = t / per_n, r = t % per_n;
  int p = r / (KC / 4), cq = r % (KC / 4);
  float cs = CSAf[n * KHW + p];
  const short* src = (const short*)(NFT + ((size_t)n * KHW + p) * KC) + cq * 4;
  short4v v = *(const short4v*)src;
  short4v o;
  #pragma unroll
  for (int j = 0; j < 4; j++) {
    short s = v[j];
    bf16 hb = *reinterpret_cast<bf16*>(&s);
    bf16 res = __float2bfloat16(__bfloat162float(hb) * cs);
    o[j] = *reinterpret_cast<short*>(&res);
  }
  int y = p / KH, x = p % KH;
  short* dst = (short*)(Zpad + ((size_t)n * KPW * KPW + (size_t)(y + 1) * KPW + (x + 1)) * KC) + cq * 4;
  *(short4v*)dst = o;
}

// ---------------- GEMM1: U = w1s x NFcg; pipelined BK=64 template, XCD-swizzled ----------------
// 800 blocks. Tile: M=64 (w1s rows), N=128 (c), K=1600 (25 steps of 64).
__global__ __launch_bounds__(256) void k_gemmU(const short* __restrict__ w1s,
                                               const short* __restrict__ NFcg,
                                               bf16* __restrict__ Uc,
                                               bf16* __restrict__ Usc) {
  __shared__ __align__(16) short smem[24576];  // As[2][4096] | Bs[2][8192] (48 KB); reused as Cs[64][136]
  short* As = smem;                            // buf stride 4096 shorts (8 KB)
  short* Bs = smem + 8192;                     // buf stride 8192 shorts (16 KB)
  short* Cs = smem;
  int b = blockIdx.x;
  int workid = (b & 7) * 100 + (b >> 3);       // bijective, 800 % 8 == 0
  int pair = workid / 20;                      // 0..39 : (n, c0 tile)
  int th = workid % 20;                        // 0..19 : (tau, half)
  int n = pair >> 2, c0 = (pair & 3) * 128;
  int tau = th >> 1, half = th & 1;
  int m0 = tau * 128 + half * 64;
  int tid = threadIdx.x, lane = tid & 63, wave = tid >> 6;
  int quad = lane >> 4, l15 = lane & 15;
  int wm = (wave & 1) * 32, wn = (wave >> 1) * 64;
  int sk = ((tid & 7) ^ ((tid >> 3) & 7)) * 8; // pre-swizzled 16B-chunk (shorts)
  int rowg = tid >> 3;                          // 0..31
  const short* Bb = NFcg + (size_t)n * KC * KHW;
  const short* pA[2];
  #pragma unroll
  for (int g = 0; g < 2; g++)
    pA[g] = w1s + (size_t)(m0 + g * 32 + rowg) * KHW + sk;
  const short* pB[4];
  #pragma unroll
  for (int g = 0; g < 4; g++)
    pB[g] = Bb + (size_t)(c0 + g * 32 + rowg) * KHW + sk;
  char* lA = (char*)As + tid * 16;
  char* lB = (char*)Bs + tid * 16;
  int bq = (l15 >> 2) & 1;
  int qx = (quad ^ (l15 & 3)) * 8;
  int koff0 = 32 * bq + qx;
  int koff1 = 32 * (1 - bq) + qx;
  f32x4 acc[2][4] = {};
  // prologue: stage step 0 into buf 0
  gload16(pA[0], lA); gload16(pA[1], lA + 4096);
  gload16(pB[0], lB); gload16(pB[1], lB + 4096);
  gload16(pB[2], lB + 8192); gload16(pB[3], lB + 12288);
  const int NS = 25;
  for (int s = 0; s < NS; s++) {
    int cb = s & 1, nb = cb ^ 1;
    if (s + 1 < NS) {
      int off = (s + 1) * 64;
      char* la = lA + nb * 8192;               // As buf stride in bytes
      char* lb = lB + nb * 16384;              // Bs buf stride in bytes
      gload16(pA[0] + off, la); gload16(pA[1] + off, la + 4096);
      gload16(pB[0] + off, lb); gload16(pB[1] + off, lb + 4096);
      gload16(pB[2] + off, lb + 8192); gload16(pB[3] + off, lb + 12288);
      asm volatile("s_waitcnt vmcnt(6)" ::: "memory");   // current buf's 6 done; next 6 in flight
    } else {
      asm volatile("s_waitcnt vmcnt(0)" ::: "memory");
    }
    __builtin_amdgcn_s_barrier();
    __builtin_amdgcn_sched_barrier(0);
    const short* Ab = As + cb * 4096;
    const short* Bbf = Bs + cb * 8192;
    #pragma unroll
    for (int ks = 0; ks < 2; ks++) {
      int ko = (ks == 0) ? koff0 : koff1;
      short8 av[2], bv[4];
      #pragma unroll
      for (int t = 0; t < 2; t++) av[t] = *(const short8*)&Ab[(wm + t * 16 + l15) * 64 + ko];
      #pragma unroll
      for (int t = 0; t < 4; t++) bv[t] = *(const short8*)&Bbf[(wn + t * 16 + l15) * 64 + ko];
      #pragma unroll
      for (int ti = 0; ti < 2; ti++)
        #pragma unroll
        for (int tj = 0; tj < 4; tj++)
          acc[ti][tj] = __builtin_amdgcn_mfma_f32_16x16x32_bf16(av[ti], bv[tj], acc[ti][tj], 0, 0, 0);
    }
    __builtin_amdgcn_s_barrier();              // all reads consumed; safe to overwrite cb
  }
  // epilogue: bf16 transpose via Cs, then coalesced store
  #pragma unroll
  for (int ti = 0; ti < 2; ti++) {
    int lr = wm + ti * 16 + quad * 4;
    #pragma unroll
    for (int tj = 0; tj < 4; tj++) {
      int lc = wn + tj * 16 + l15;
      #pragma unroll
      for (int r = 0; r < 4; r++)
        *(bf16*)&Cs[(lr + r) * 136 + lc] = __float2bfloat16(acc[ti][tj][r]);
    }
  }
  __syncthreads();
  int dyq = tau / 3, dxq = tau % 3;
  #pragma unroll
  for (int pass = 0; pass < 4; pass++) {
    int row = pass * 16 + (tid >> 4);          // 0..63
    int col = (tid & 15) * 8;                  // 0..127
    if (tau < 9) {
      *(float4*)&Uc[((size_t)((n * 3 + dyq) * 128 + half * 64 + row)) * 1536 + dxq * 512 + c0 + col] =
          *(const float4*)&Cs[row * 136 + col];
    } else {
      *(float4*)&Usc[((size_t)(n * 128 + half * 64 + row)) * 512 + c0 + col] =
          *(const float4*)&Cs[row * 136 + col];
    }
  }
}

// ---------------- convh: dy-split pipelined GEMM, M=128(o) x N=64(p), K=1536 (conv) / 512 (sc)
__global__ __launch_bounds__(256) void k_convh(const short* __restrict__ Uc,
                                               const short* __restrict__ Usc,
                                               const short* __restrict__ Zpad,
                                               float* __restrict__ Hpart) {
  __shared__ __align__(16) short smem[24576];  // As[2][8192] | Bs[2][4096]  (48 KB)
  short* As = smem;
  short* Bs = smem + 16384;
  int b = blockIdx.x;
  int wgid = (b & 7) * 125 + (b >> 3);         // bijective, 1000 % 8 == 0
  int n = wgid / 100, rest = wgid % 100;
  int dy = rest / 25, pt = rest % 25;
  int p0 = pt * 64;
  int tid = threadIdx.x, lane = tid & 63, wave = tid >> 6;
  int quad = lane >> 4, l15 = lane & 15;
  int wm = (wave & 1) * 64, wn = (wave >> 1) * 32;
  // staging: pre-swizzled global source; LDS stays linear (rule #21)
  int sk = ((tid & 7) ^ ((tid >> 3) & 7)) * 8;   // swizzled 16B-chunk (shorts)
  int rowg = tid >> 3;                            // 0..31
  bool isconv = (dy < 3);
  const short* Zb = Zpad + (size_t)n * KPW * KPW * KC;
  const short* Abase = isconv ? Uc + ((size_t)((n * 3 + dy) * 128)) * 1536
                              : Usc + ((size_t)(n * 128)) * 512;
  int astr = isconv ? 1536 : 512;
  const short* pA[4];
  #pragma unroll
  for (int g = 0; g < 4; g++)
    pA[g] = Abase + (size_t)(g * 32 + rowg) * astr + sk;
  const short* pB[2];
  #pragma unroll
  for (int g = 0; g < 2; g++) {
    int p = p0 + g * 32 + rowg;
    int y = p / KH, x = p % KH;
    int yy = isconv ? (y + dy) : (y + 1);
    int xx = isconv ? x : (x + 1);
    pB[g] = Zb + ((size_t)yy * KPW + xx) * KC + sk;
  }
  char* lA = (char*)As + tid * 16;
  char* lB = (char*)Bs + tid * 16;
  int NS = isconv ? 24 : 8;
  // swizzled ds_read k offsets (shorts)
  int bq = (l15 >> 2) & 1;
  int qx = (quad ^ (l15 & 3)) * 8;
  int koff0 = 32 * bq + qx;
  int koff1 = 32 * (1 - bq) + qx;
  f32x4 acc[4][2] = {};
  // prologue: stage step 0 into buf 0
  gload16(pA[0], lA); gload16(pA[1], lA + 4096);
  gload16(pA[2], lA + 8192); gload16(pA[3], lA + 12288);
  gload16(pB[0], lB); gload16(pB[1], lB + 4096);
  for (int s = 0; s < NS; s++) {
    int cb = s & 1, nb = cb ^ 1;
    if (s + 1 < NS) {
      int off = (s + 1) * 64;
      char* la = lA + nb * 16384;
      char* lb = lB + nb * 8192;
      gload16(pA[0] + off, la); gload16(pA[1] + off, la + 4096);
      gload16(pA[2] + off, la + 8192); gload16(pA[3] + off, la + 12288);
      gload16(pB[0] + off, lb); gload16(pB[1] + off, lb + 4096);
      asm volatile("s_waitcnt vmcnt(6)" ::: "memory");   // current buf done; next 6 in flight
    } else {
      asm volatile("s_waitcnt vmcnt(0)" ::: "memory");
    }
    __builtin_amdgcn_s_barrier();
    __builtin_amdgcn_sched_barrier(0);
    const short* Ab = As + cb * 8192;
    const short* Bb = Bs + cb * 4096;
    #pragma unroll
    for (int ks = 0; ks < 2; ks++) {
      int ko = (ks == 0) ? koff0 : koff1;
      short8 av[4], bv[2];
      #pragma unroll
      for (int t = 0; t < 4; t++) av[t] = *(const short8*)&Ab[(wm + t * 16 + l15) * 64 + ko];
      #pragma unroll
      for (int t = 0; t < 2; t++) bv[t] = *(const short8*)&Bb[(wn + t * 16 + l15) * 64 + ko];
      #pragma unroll
      for (int ti = 0; ti < 4; ti++)
        #pragma unroll
        for (int tj = 0; tj < 2; tj++)
          acc[ti][tj] = __builtin_amdgcn_mfma_f32_16x16x32_bf16(av[ti], bv[tj], acc[ti][tj], 0, 0, 0);
    }
    __builtin_amdgcn_s_barrier();              // lgkm drained before MFMA; safe to overwrite cb
  }
  float* cbp = Hpart + ((size_t)(dy * KN + n)) * KOC * KHW;
  #pragma unroll
  for (int ti = 0; ti < 4; ti++) {
    int o = wm + ti * 16 + quad * 4;
    #pragma unroll
    for (int tj = 0; tj < 2; tj++) {
      int q = p0 + wn + tj * 16 + l15;
      #pragma unroll
      for (int r = 0; r < 4; r++)
        cbp[(size_t)(o + r) * KHW + q] = acc[ti][tj][r];
    }
  }
}

// hpadT[n, y+1, x+1, o] = bf16(relu(b1[o] + Hpart[0]+Hpart[1]+Hpart[2]))
__global__ void k_hprep3(const float* __restrict__ Hpart, const float* __restrict__ b1,
                         bf16* __restrict__ hpadT) {
  __shared__ float T[32][132];
  int n = blockIdx.y, p0 = blockIdx.x * 32;
  int tx = threadIdx.x, ty = threadIdx.y;
  const size_t str = (size_t)KN * KOC * KHW;
  const float* hb = Hpart + (size_t)n * KOC * KHW;
  #pragma unroll
  for (int oc = 0; oc < 16; oc++) {
    int o = oc * 8 + ty;
    size_t off = (size_t)o * KHW + p0 + tx;
    T[tx][o] = fmaxf(hb[off] + hb[str + off] + hb[2 * str + off] + b1[o], 0.0f);
  }
  __syncthreads();
  bf16* hp = hpadT + (size_t)n * KPW * KPW * KOC;
  #pragma unroll
  for (int pc = 0; pc < 4; pc++) {
    int pl = ty * 4 + pc;
    int pp = p0 + pl;
    int yy = pp / KH, xx = pp % KH;
    bf16* row = hp + ((size_t)(yy + 1) * KPW + (xx + 1)) * KOC;
    #pragma unroll
    for (int u = 0; u < 4; u++) row[tx * 4 + u] = __float2bfloat16(T[pl][tx * 4 + u]);
  }
}

// ---------------- conv2 (3x3, 128->128): same pipelined template, K=384 per dy ----------------
// 750 blocks = 10n * 3dy * 25pt, bijective XCD swizzle (750 = 8*93+6).
__global__ __launch_bounds__(256) void k_conv2(const short* __restrict__ w2p,
                                               const short* __restrict__ hpadT,
                                               float* __restrict__ Cpart) {
  __shared__ __align__(16) short smem[24576];
  short* As = smem;
  short* Bs = smem + 16384;
  int b = blockIdx.x;
  int xcd = b & 7, bi = b >> 3;
  int wgid = (xcd < 6 ? xcd * 94 : 6 * 94 + (xcd - 6) * 93) + bi;
  int n = wgid / 75, rest = wgid % 75;
  int dy = rest / 25, pt = rest % 25;
  int p0 = pt * 64;
  int tid = threadIdx.x, lane = tid & 63, wave = tid >> 6;
  int quad = lane >> 4, l15 = lane & 15;
  int wm = (wave & 1) * 64, wn = (wave >> 1) * 32;
  int sk = ((tid & 7) ^ ((tid >> 3) & 7)) * 8;
  int rowg = tid >> 3;
  const short* hb = hpadT + (size_t)n * KPW * KPW * KOC;
  const short* pA[4];
  #pragma unroll
  for (int g = 0; g < 4; g++)
    pA[g] = w2p + (size_t)(g * 32 + rowg) * (9 * KOC) + dy * 384 + sk;
  const short* pB[2];
  #pragma unroll
  for (int g = 0; g < 2; g++) {
    int p = p0 + g * 32 + rowg;
    int y = p / KH, x = p % KH;
    pB[g] = hb + ((size_t)(y + dy) * KPW + x) * KOC + sk;   // k = dx*128+c contiguous
  }
  char* lA = (char*)As + tid * 16;
  char* lB = (char*)Bs + tid * 16;
  const int NS = 6;                            // K = 384 = 6 * 64
  int bq = (l15 >> 2) & 1;
  int qx = (quad ^ (l15 & 3)) * 8;
  int koff0 = 32 * bq + qx;
  int koff1 = 32 * (1 - bq) + qx;
  f32x4 acc[4][2] = {};
  gload16(pA[0], lA); gload16(pA[1], lA + 4096);
  gload16(pA[2], lA + 8192); gload16(pA[3], lA + 12288);
  gload16(pB[0], lB); gload16(pB[1], lB + 4096);
  for (int s = 0; s < NS; s++) {
    int cb = s & 1, nb = cb ^ 1;
    if (s + 1 < NS) {
      int off = (s + 1) * 64;
      char* la = lA + nb * 16384;
      char* lb = lB + nb * 8192;
      gload16(pA[0] + off, la); gload16(pA[1] + off, la + 4096);
      gload16(pA[2] + off, la + 8192); gload16(pA[3] + off, la + 12288);
      gload16(pB[0] + off, lb); gload16(pB[1] + off, lb + 4096);
      asm volatile("s_waitcnt vmcnt(6)" ::: "memory");
    } else {
      asm volatile("s_waitcnt vmcnt(0)" ::: "memory");
    }
    __builtin_amdgcn_s_barrier();
    __builtin_amdgcn_sched_barrier(0);
    const short* Ab = As + cb * 8192;
    const short* Bb = Bs + cb * 4096;
    #pragma unroll
    for (int ks = 0; ks < 2; ks++) {
      int ko = (ks == 0) ? koff0 : koff1;
      short8 av[4], bv[2];
      #pragma unroll
      for (int t = 0; t < 4; t++) av[t] = *(const short8*)&Ab[(wm + t * 16 + l15) * 64 + ko];
      #pragma unroll
      for (int t = 0; t < 2; t++) bv[t] = *(const short8*)&Bb[(wn + t * 16 + l15) * 64 + ko];
      #pragma unroll
      for (int ti = 0; ti < 4; ti++)
        #pragma unroll
        for (int tj = 0; tj < 2; tj++)
          acc[ti][tj] = __builtin_amdgcn_mfma_f32_16x16x32_bf16(av[ti], bv[tj], acc[ti][tj], 0, 0, 0);
    }
    __builtin_amdgcn_s_barrier();
  }
  float* cbp = Cpart + ((size_t)(dy * KN + n)) * KOC * KHW;
  #pragma unroll
  for (int ti = 0; ti < 4; ti++) {
    int o = wm + ti * 16 + quad * 4;
    #pragma unroll
    for (int tj = 0; tj < 2; tj++) {
      int q = p0 + wn + tj * 16 + l15;
      #pragma unroll
      for (int r = 0; r < 4; r++)
        cbp[(size_t)(o + r) * KHW + q] = acc[ti][tj][r];
    }
  }
}

// out = relu(sum_dy Cpart + b2 + shortcut(Hpart[3]) + bs)
__global__ void k_final2(const float* __restrict__ Cpart, const float* __restrict__ Hpart,
                         const float* __restrict__ b2, const float* __restrict__ bs,
                         float* __restrict__ out) {
  int t = blockIdx.x * 256 + threadIdx.x;
  if (t >= KN * KOC * KHW) return;
  int o = (t / KHW) % KOC;
  const size_t stride = (size_t)KN * KOC * KHW;
  float v = Cpart[t] + Cpart[stride + t] + Cpart[2 * stride + t] +
            Hpart[3 * stride + t] + b2[o] + bs[o];
  out[t] = fmaxf(v, 0.0f);
}

// ---------------- launch ----------------
extern "C" void kernel_launch(void* const* d_in, const int* in_sizes, int n_in,
                              void* d_out, int out_size, void* d_ws, size_t ws_size,
                              hipStream_t stream) {
  const float* feats = (const float*)d_in[0];
  const float* sisms = (const float*)d_in[1];
  const float* w1 = (const float*)d_in[2];
  const float* b1 = (const float*)d_in[3];
  const float* w2 = (const float*)d_in[4];
  const float* b2 = (const float*)d_in[5];
  const float* wsc = (const float*)d_in[6];
  const float* bsc = (const float*)d_in[7];
  float* out = (float*)d_out;

  char* w = (char*)d_ws;
  auto carve = [&](size_t bytes) -> void* {
    void* p = (void*)w;
    w += (bytes + 255) & ~(size_t)255;
    return p;
  };
  bf16* NFT   = (bf16*)carve((size_t)KN * KHW * KC * 2);          // 16.4 MB
  bf16* NFcg  = (bf16*)carve((size_t)KN * KC * KHW * 2);          // 16.4 MB
  bf16* Uc    = (bf16*)carve((size_t)KN * 3 * 128 * 1536 * 2);    // 11.8 MB
  bf16* Usc   = (bf16*)carve((size_t)KN * 128 * 512 * 2);         // 1.3 MB
  bf16* w1s   = (bf16*)carve((size_t)KM * KHW * 2);               // 4.1 MB
  bf16* Zpad  = (bf16*)carve((size_t)KN * KPW * KPW * KC * 2);    // 18.1 MB
  bf16* hpadT = (bf16*)carve((size_t)KN * KPW * KPW * KOC * 2);   // 4.5 MB
  float* Hpart = (float*)carve((size_t)4 * KN * KOC * KHW * 4);   // 32.8 MB
  float* Cpart = (float*)carve((size_t)3 * KN * KOC * KHW * 4);   // 24.6 MB
  bf16* w2p   = (bf16*)carve((size_t)KOC * 9 * KOC * 2);
  double* psbuf = (double*)carve((size_t)4 * KN * KHW * 8);
  double* rnorm = (double*)carve((size_t)KN * KHW * 8);
  double* vpp   = (double*)carve((size_t)KN * KC * 50 * 8);       // 2.05 MB
  double* SIV   = (double*)carve((size_t)KN * KC * 8);
  double* cmp   = (double*)carve((size_t)8 * KN * KN * KHW * 8);  // 10.2 MB
  double* cm    = (double*)carve((size_t)KN * KN * KHW * 8);
  double* tbuf  = (double*)carve((size_t)KN * KN * 8);
  double* CSAd  = (double*)carve((size_t)KN * KHW * 8);
  float* CSAf   = (float*)carve((size_t)KN * KHW * 4);
  int* idxb     = (int*)carve((size_t)KN * KHW * 4);

  k_zborder<<<513, 256, 0, stream>>>(Zpad, hpadT);

  k_rnormp<<<dim3(63, 4), 256, 0, stream>>>(feats, psbuf);
  k_rnormc<<<63, 256, 0, stream>>>(psbuf, rnorm);
  k_nft<<<dim3(50, 16, KN), dim3(32, 8), 0, stream>>>(feats, rnorm, sisms, NFT, vpp);
  k_sivnorm2<<<KN, 512, 0, stream>>>(vpp, SIV);
  k_cmP<<<dim3(7, 8, KN), 256, 0, stream>>>(feats, SIV, cmp);
  k_cmB<<<625, 256, 0, stream>>>(cmp, rnorm, cm);
  k_cmnorm<<<KN * KN, 256, 0, stream>>>(cm);
  k_st<<<KN * KN, 256, 0, stream>>>(cm, tbuf);
  k_csa<<<KN, 256, 0, stream>>>(cm, tbuf, CSAd, CSAf);
  k_rank<<<1000, 256, 0, stream>>>(CSAd, idxb);

  k_prepw1s<<<KM * KHW / 256, 256, 0, stream>>>(w1, wsc, w1s);
  k_prepw2<<<576, 256, 0, stream>>>(w2, w2p);
  k_gath2<<<dim3(50, 16, KN), dim3(32, 8), 0, stream>>>((const short*)NFT, idxb, (short*)NFcg);
  k_zprep<<<KN * KHW * (KC / 4) / 256, 256, 0, stream>>>(NFT, CSAf, Zpad);

  k_gemmU<<<800, 256, 0, stream>>>((const short*)w1s, (const short*)NFcg, Uc, Usc);
  k_convh<<<1000, 256, 0, stream>>>((const short*)Uc, (const short*)Usc,
                                    (const short*)Zpad, Hpart);
  k_hprep3<<<dim3(50, KN), dim3(32, 8), 0, stream>>>(Hpart, b1, hpadT);
  k_conv2<<<750, 256, 0, stream>>>((const short*)w2p, (const short*)hpadT, Cpart);
  k_final2<<<8000, 256, 0, stream>>>(Cpart, Hpart, b2, bsc, out);
}

// Round 7
// 270.966 us; speedup vs baseline: 1.1125x; 1.0484x over previous
//
#include <hip/hip_runtime.h>
#include <hip/hip_bf16.h>
#include <math.h>

typedef short short8 __attribute__((ext_vector_type(8)));
typedef short short4v __attribute__((ext_vector_type(4)));
typedef float f32x4 __attribute__((ext_vector_type(4)));
typedef __hip_bfloat16 bf16;

// problem constants
#define KN 10
#define KC 512
#define KHW 1600
#define KH 40
#define KOC 128
#define KPW 42   // padded spatial (40+2)
#define KM 1280  // stacked M: 9 conv taps * 128 + 128 shortcut

// direct global->LDS DMA, 16B per lane. LDS dest must be wave-uniform base + lane*16.
__device__ __forceinline__ void gload16(const void* g, void* l) {
  __builtin_amdgcn_global_load_lds(
      (const __attribute__((address_space(1))) unsigned int*)g,
      (__attribute__((address_space(3))) unsigned int*)l, 16, 0, 0);
}

// ---------------- block reduction helpers (fp64) ----------------
__device__ __forceinline__ double blockReduceSumD(double v) {
  __shared__ double tmpS[8];
  int lane = threadIdx.x & 63, wv = threadIdx.x >> 6;
  #pragma unroll
  for (int o = 32; o > 0; o >>= 1) v += __shfl_down(v, o);
  if (lane == 0) tmpS[wv] = v;
  __syncthreads();
  if (threadIdx.x == 0) {
    int nw = (blockDim.x + 63) >> 6;
    double s = 0;
    for (int i = 0; i < nw; i++) s += tmpS[i];
    tmpS[0] = s;
  }
  __syncthreads();
  double r = tmpS[0];
  __syncthreads();
  return r;
}

__device__ __forceinline__ double blockReduceMinD(double v) {
  __shared__ double tmpMn[8];
  int lane = threadIdx.x & 63, wv = threadIdx.x >> 6;
  #pragma unroll
  for (int o = 32; o > 0; o >>= 1) v = fmin(v, __shfl_down(v, o));
  if (lane == 0) tmpMn[wv] = v;
  __syncthreads();
  if (threadIdx.x == 0) {
    int nw = (blockDim.x + 63) >> 6;
    double s = tmpMn[0];
    for (int i = 1; i < nw; i++) s = fmin(s, tmpMn[i]);
    tmpMn[0] = s;
  }
  __syncthreads();
  double r = tmpMn[0];
  __syncthreads();
  return r;
}

__device__ __forceinline__ double blockReduceMaxD(double v) {
  __shared__ double tmpMx[8];
  int lane = threadIdx.x & 63, wv = threadIdx.x >> 6;
  #pragma unroll
  for (int o = 32; o > 0; o >>= 1) v = fmax(v, __shfl_down(v, o));
  if (lane == 0) tmpMx[wv] = v;
  __syncthreads();
  if (threadIdx.x == 0) {
    int nw = (blockDim.x + 63) >> 6;
    double s = tmpMx[0];
    for (int i = 1; i < nw; i++) s = fmax(s, tmpMx[i]);
    tmpMx[0] = s;
  }
  __syncthreads();
  double r = tmpMx[0];
  __syncthreads();
  return r;
}

// ---------------- small chain (fp64 for argsort stability) ----------------

// 16 channel-slices of 32: 1008 blocks
__global__ void k_rnormp(const float* __restrict__ feats, double* __restrict__ ps) {
  int t = blockIdx.x * 256 + threadIdx.x;
  if (t >= KN * KHW) return;
  int ci = blockIdx.y;
  int n = t / KHW, k = t % KHW;
  const float* p = feats + (size_t)n * KC * KHW + (size_t)ci * 32 * KHW + k;
  double s = 0.0;
  #pragma unroll
  for (int c = 0; c < 32; ++c) { double v = p[(size_t)c * KHW]; s += v * v; }
  ps[(size_t)ci * KN * KHW + t] = s;
}

__global__ void k_rnormc(const double* __restrict__ ps, double* __restrict__ rnorm) {
  int t = blockIdx.x * 256 + threadIdx.x;
  if (t >= KN * KHW) return;
  double s = 0;
  #pragma unroll
  for (int ci = 0; ci < 16; ci++) s += ps[(size_t)ci * KN * KHW + t];
  double nn = sqrt(s);
  if (nn < 1e-12) nn = 1e-12;
  rnorm[t] = 1.0 / nn;
}

// NFT[n,k,c] = bf16(feats[n,c,k] * rnorm[n,k]); also emits SIV pre-partials
__global__ void k_nft(const float* __restrict__ feats, const double* __restrict__ rnorm,
                      const float* __restrict__ sism, bf16* __restrict__ NFT,
                      double* __restrict__ vpp) {
  __shared__ float T[32][33];
  int n = blockIdx.z, k0 = blockIdx.x * 32, c0 = blockIdx.y * 32;
  int tx = threadIdx.x, ty = threadIdx.y;
  const float* fb = feats + ((size_t)n * KC + c0) * KHW + k0;
  #pragma unroll
  for (int ii = 0; ii < 4; ii++) {
    int cl = ty * 4 + ii;
    T[cl][tx] = fb[(size_t)cl * KHW + tx];
  }
  __syncthreads();
  bf16* ob = NFT + ((size_t)n * KHW + k0) * KC + c0;
  #pragma unroll
  for (int ii = 0; ii < 4; ii++) {
    int kl = ty * 4 + ii;
    float r = (float)rnorm[n * KHW + k0 + kl];
    ob[(size_t)kl * KC + tx] = __float2bfloat16(T[tx][kl] * r);
  }
  double rs = rnorm[n * KHW + k0 + tx] * (double)sism[n * KHW + k0 + tx];
  #pragma unroll
  for (int ii = 0; ii < 4; ii++) {
    int cl = ty * 4 + ii;
    double v = (double)T[cl][tx] * rs;
    #pragma unroll
    for (int o = 16; o > 0; o >>= 1) v += __shfl_down(v, o, 32);
    if (tx == 0) vpp[((size_t)n * KC + c0 + cl) * 50 + k0 / 32] = v;
  }
}

__global__ void k_sivnorm2(const double* __restrict__ vpp, double* __restrict__ SIV) {
  int n = blockIdx.x, c = threadIdx.x;   // 512 threads
  const double* p = vpp + ((size_t)n * KC + c) * 50;
  double acc = 0;
  #pragma unroll 5
  for (int j = 0; j < 50; j++) acc += p[j];
  acc /= (double)KHW;
  double s2 = blockReduceSumD(acc * acc);
  double nn = sqrt(s2);
  if (nn < 1e-12) nn = 1e-12;
  SIV[n * KC + c] = acc / nn;
}

// 16 channel-slices of 32: 1120 blocks
__global__ void k_cmP(const float* __restrict__ feats, const double* __restrict__ SIV,
                      double* __restrict__ cmp) {
  __shared__ double sv[KN][32];
  int kc = blockIdx.x, ci = blockIdx.y, n = blockIdx.z;
  for (int t = threadIdx.x; t < KN * 32; t += 256) {
    int m = t / 32, c = t % 32;
    sv[m][c] = SIV[m * KC + ci * 32 + c];
  }
  __syncthreads();
  int k = kc * 256 + threadIdx.x;
  if (k >= KHW) return;
  const float* f = feats + ((size_t)n * KC + ci * 32) * KHW + k;
  double acc[KN];
  #pragma unroll
  for (int m = 0; m < KN; m++) acc[m] = 0.0;
  for (int c = 0; c < 32; ++c) {
    double fv = f[(size_t)c * KHW];
    #pragma unroll
    for (int m = 0; m < KN; m++) acc[m] += fv * sv[m][c];
  }
  const size_t str = (size_t)KN * KN * KHW;
  #pragma unroll
  for (int m = 0; m < KN; m++)
    cmp[(size_t)ci * str + ((size_t)n * KN + m) * KHW + k] = acc[m];
}

// fused cmB + cmnorm: one block (512 thr) per (n,m) row; sum 16 slices, scale by rnorm,
// row-L2-normalize, single write pass.
__global__ void k_cmBN(const double* __restrict__ cmp, const double* __restrict__ rnorm,
                       double* __restrict__ cm) {
  int b = blockIdx.x;                       // 100 = n*KN + m
  int n = b / KN;
  const size_t str = (size_t)KN * KN * KHW;
  const size_t rb = (size_t)b * KHW;
  double v[4];
  int cnt = 0;
  double ss = 0;
  for (int k = threadIdx.x; k < KHW; k += 512) {
    double s = 0;
    #pragma unroll
    for (int ci = 0; ci < 16; ci++) s += cmp[ci * str + rb + k];
    s *= rnorm[n * KHW + k];
    v[cnt++] = s;
    ss += s * s;
  }
  ss = blockReduceSumD(ss);
  double nn = sqrt(ss);
  if (nn < 1e-12) nn = 1e-12;
  double rn = 1.0 / nn;
  cnt = 0;
  for (int k = threadIdx.x; k < KHW; k += 512) cm[rb + k] = v[cnt++] * rn;
}

__global__ void k_st(const double* __restrict__ cm, double* __restrict__ tbuf) {
  int b = blockIdx.x;
  int n = b / KN, m = b % KN;
  const double* base = cm + (size_t)n * KN * KHW;
  double acc = 0;
  for (int k = threadIdx.x; k < KHW; k += 256) {
    double S = 0;
    #pragma unroll
    for (int mm = 0; mm < KN; mm++) S += base[(size_t)mm * KHW + k];
    acc += base[(size_t)m * KHW + k] * S;
  }
  acc = blockReduceSumD(acc);
  if (threadIdx.x == 0) tbuf[b] = acc;
}

__global__ void k_csa(const double* __restrict__ cm, const double* __restrict__ tbuf,
                      double* __restrict__ CSAd, float* __restrict__ CSAf) {
  __shared__ double w[KN];
  int n = blockIdx.x, tid = threadIdx.x;
  if (tid == 0) {
    double v[KN], mx = -1e300;
    #pragma unroll
    for (int m = 0; m < KN; m++) { v[m] = tbuf[n * KN + m]; mx = fmax(mx, v[m]); }
    double s = 0;
    #pragma unroll
    for (int m = 0; m < KN; m++) { v[m] = exp(v[m] - mx); s += v[m]; }
    #pragma unroll
    for (int m = 0; m < KN; m++) w[m] = v[m] / s;
  }
  __syncthreads();
  double v[7];
  int cnt = 0;
  double lmin = 1e300, lmax = -1e300;
  for (int k = tid; k < KHW; k += 256) {
    double a = 0;
    #pragma unroll
    for (int m = 0; m < KN; m++) a += cm[((size_t)n * KN + m) * KHW + k] * w[m];
    v[cnt++] = a;
    lmin = fmin(lmin, a);
    lmax = fmax(lmax, a);
  }
  double mn = blockReduceMinD(lmin);
  double mx = blockReduceMaxD(lmax);
  double inv = 1.0 / (mx - mn + 1e-12);
  cnt = 0;
  for (int k = tid; k < KHW; k += 256) {
    double nv = (v[cnt++] - mn) * inv;
    CSAd[(size_t)n * KHW + k] = nv;
    CSAf[(size_t)n * KHW + k] = (float)nv;
  }
}

// rank-based stable descending argsort: idx[rank[i]] = i
// wave-parallel: 1000 blocks; block = 16 i's (4 waves x 4), lanes cover j.
__global__ void k_rank(const double* __restrict__ CSAd, int* __restrict__ idx) {
  __shared__ double key[KHW];
  int b = blockIdx.x;
  int n = b / 100, it = b % 100;
  const double* src = CSAd + (size_t)n * KHW;
  for (int j = threadIdx.x; j < KHW; j += 256) key[j] = src[j];
  __syncthreads();
  int wave = threadIdx.x >> 6, lane = threadIdx.x & 63;
  int i0 = it * 16 + wave * 4;
  double ki[4];
  #pragma unroll
  for (int ii = 0; ii < 4; ii++) ki[ii] = key[i0 + ii];
  int r[4] = {0, 0, 0, 0};
  #pragma unroll
  for (int q = 0; q < 25; q++) {
    int j = q * 64 + lane;
    double kj = key[j];
    #pragma unroll
    for (int ii = 0; ii < 4; ii++) {
      int i = i0 + ii;
      r[ii] += (kj > ki[ii]) || (kj == ki[ii] && j < i);
    }
  }
  #pragma unroll
  for (int ii = 0; ii < 4; ii++) {
    int v = r[ii];
    #pragma unroll
    for (int o = 32; o > 0; o >>= 1) v += __shfl_down(v, o);
    if (lane == 0) idx[n * KHW + v] = i0 + ii;
  }
}

// ---------------- stacked weights (n-independent): w1s[(tau,o)][i] ----------------
__global__ void k_prepw1s(const float* __restrict__ w1, const float* __restrict__ wsc,
                          bf16* __restrict__ w1s) {
  int t = blockIdx.x * 256 + threadIdx.x;   // over KM*KHW
  int m = t / KHW, i = t % KHW;
  int tau = m >> 7, o = m & 127;
  float v = (tau < 9) ? w1[((size_t)o * KHW + i) * 9 + tau]
                      : wsc[(size_t)o * KHW + i];
  w1s[t] = __float2bfloat16(v);
}

__global__ void k_prepw2(const float* __restrict__ w2, bf16* __restrict__ w2p) {
  int t = blockIdx.x * 256 + threadIdx.x;
  if (t >= KOC * 9 * KOC) return;
  int o = t / (9 * KOC), r = t % (9 * KOC);
  int s = r / KOC, i = r % KOC;
  w2p[t] = __float2bfloat16(w2[(size_t)o * 9 * KOC + (size_t)i * 9 + s]);
}

// ---------------- zero only the padding borders of Zpad and hpadT ----------------
__global__ void k_zborder(bf16* __restrict__ Zpad, bf16* __restrict__ hpadT) {
  int t = blockIdx.x * 256 + threadIdx.x;
  const int ZW = KN * 164 * (KC / 8);       // 104960
  const int HWm = KN * 164 * (KOC / 8);     // 26240
  int b;
  if (t < ZW) {
    int n = t / (164 * 64), r = t % (164 * 64);
    b = r / 64;
    int c8 = r % 64;
    int y, x;
    if (b < 42) { y = 0; x = b; }
    else if (b < 84) { y = 41; x = b - 42; }
    else if (b < 124) { y = b - 84 + 1; x = 0; }
    else { y = b - 124 + 1; x = 41; }
    short8 z = {};
    *(short8*)((short*)Zpad + ((size_t)n * KPW * KPW + (size_t)y * KPW + x) * KC + c8 * 8) = z;
  } else if (t < ZW + HWm) {
    int u = t - ZW;
    int n = u / (164 * 16), r = u % (164 * 16);
    b = r / 16;
    int c8 = r % 16;
    int y, x;
    if (b < 42) { y = 0; x = b; }
    else if (b < 84) { y = 41; x = b - 42; }
    else if (b < 124) { y = b - 84 + 1; x = 0; }
    else { y = b - 124 + 1; x = 41; }
    short8 z = {};
    *(short8*)((short*)hpadT + ((size_t)n * KPW * KPW + (size_t)y * KPW + x) * KOC + c8 * 8) = z;
  }
}

// ---------------- NF column gather: NFcg[n][c][i] = NFT[n][idx[i]][c] ----------------
__global__ void k_gath2(const short* __restrict__ NFT, const int* __restrict__ idx,
                        short* __restrict__ NFcg) {
  __shared__ short T[32][33];
  int i0 = blockIdx.x * 32, c0 = blockIdx.y * 32, n = blockIdx.z;
  int tx = threadIdx.x, ty = threadIdx.y;
  #pragma unroll
  for (int ii = 0; ii < 4; ii++) {
    int row = ty * 4 + ii;
    int id = idx[n * KHW + i0 + row];
    T[row][tx] = NFT[((size_t)n * KHW + id) * KC + c0 + tx];
  }
  __syncthreads();
  #pragma unroll
  for (int ii = 0; ii < 4; ii++) {
    int cl = ty * 4 + ii;
    NFcg[((size_t)n * KC + c0 + cl) * KHW + i0 + tx] = T[tx][cl];
  }
}

// Zpad[n, y+1, x+1, c] = bf16(NFT[n,p,c] * CSA[n,p])
__global__ void k_zprep(const bf16* __restrict__ NFT, const float* __restrict__ CSAf,
                        bf16* __restrict__ Zpad) {
  int t = blockIdx.x * 256 + threadIdx.x;   // over KN*KHW*KC/4
  const int per_n = KHW * (KC / 4);
  int n = t / per_n, r = t % per_n;
  int p = r / (KC / 4), cq = r % (KC / 4);
  float cs = CSAf[n * KHW + p];
  const short* src = (const short*)(NFT + ((size_t)n * KHW + p) * KC) + cq * 4;
  short4v v = *(const short4v*)src;
  short4v o;
  #pragma unroll
  for (int j = 0; j < 4; j++) {
    short s = v[j];
    bf16 hb = *reinterpret_cast<bf16*>(&s);
    bf16 res = __float2bfloat16(__bfloat162float(hb) * cs);
    o[j] = *reinterpret_cast<short*>(&res);
  }
  int y = p / KH, x = p % KH;
  short* dst = (short*)(Zpad + ((size_t)n * KPW * KPW + (size_t)(y + 1) * KPW + (x + 1)) * KC) + cq * 4;
  *(short4v*)dst = o;
}

// ---------------- GEMM1: U = w1s x NFcg; pipelined BK=64 template, XCD-swizzled ----------------
// 800 blocks. Tile: M=64 (w1s rows), N=128 (c), K=1600 (25 steps of 64).
__global__ __launch_bounds__(256) void k_gemmU(const short* __restrict__ w1s,
                                               const short* __restrict__ NFcg,
                                               bf16* __restrict__ Uc,
                                               bf16* __restrict__ Usc) {
  __shared__ __align__(16) short smem[24576];  // As[2][4096] | Bs[2][8192] (48 KB); reused as Cs[64][136]
  short* As = smem;                            // buf stride 4096 shorts (8 KB)
  short* Bs = smem + 8192;                     // buf stride 8192 shorts (16 KB)
  short* Cs = smem;
  int b = blockIdx.x;
  int workid = (b & 7) * 100 + (b >> 3);       // bijective, 800 % 8 == 0
  int pair = workid / 20;                      // 0..39 : (n, c0 tile)
  int th = workid % 20;                        // 0..19 : (tau, half)
  int n = pair >> 2, c0 = (pair & 3) * 128;
  int tau = th >> 1, half = th & 1;
  int m0 = tau * 128 + half * 64;
  int tid = threadIdx.x, lane = tid & 63, wave = tid >> 6;
  int quad = lane >> 4, l15 = lane & 15;
  int wm = (wave & 1) * 32, wn = (wave >> 1) * 64;
  int sk = ((tid & 7) ^ ((tid >> 3) & 7)) * 8; // pre-swizzled 16B-chunk (shorts)
  int rowg = tid >> 3;                          // 0..31
  const short* Bb = NFcg + (size_t)n * KC * KHW;
  const short* pA[2];
  #pragma unroll
  for (int g = 0; g < 2; g++)
    pA[g] = w1s + (size_t)(m0 + g * 32 + rowg) * KHW + sk;
  const short* pB[4];
  #pragma unroll
  for (int g = 0; g < 4; g++)
    pB[g] = Bb + (size_t)(c0 + g * 32 + rowg) * KHW + sk;
  char* lA = (char*)As + tid * 16;
  char* lB = (char*)Bs + tid * 16;
  int bq = (l15 >> 2) & 1;
  int qx = (quad ^ (l15 & 3)) * 8;
  int koff0 = 32 * bq + qx;
  int koff1 = 32 * (1 - bq) + qx;
  f32x4 acc[2][4] = {};
  // prologue: stage step 0 into buf 0
  gload16(pA[0], lA); gload16(pA[1], lA + 4096);
  gload16(pB[0], lB); gload16(pB[1], lB + 4096);
  gload16(pB[2], lB + 8192); gload16(pB[3], lB + 12288);
  const int NS = 25;
  for (int s = 0; s < NS; s++) {
    int cb = s & 1, nb = cb ^ 1;
    if (s + 1 < NS) {
      int off = (s + 1) * 64;
      char* la = lA + nb * 8192;               // As buf stride in bytes
      char* lb = lB + nb * 16384;              // Bs buf stride in bytes
      gload16(pA[0] + off, la); gload16(pA[1] + off, la + 4096);
      gload16(pB[0] + off, lb); gload16(pB[1] + off, lb + 4096);
      gload16(pB[2] + off, lb + 8192); gload16(pB[3] + off, lb + 12288);
      asm volatile("s_waitcnt vmcnt(6)" ::: "memory");   // current buf's 6 done; next 6 in flight
    } else {
      asm volatile("s_waitcnt vmcnt(0)" ::: "memory");
    }
    __builtin_amdgcn_s_barrier();
    __builtin_amdgcn_sched_barrier(0);
    const short* Ab = As + cb * 4096;
    const short* Bbf = Bs + cb * 8192;
    #pragma unroll
    for (int ks = 0; ks < 2; ks++) {
      int ko = (ks == 0) ? koff0 : koff1;
      short8 av[2], bv[4];
      #pragma unroll
      for (int t = 0; t < 2; t++) av[t] = *(const short8*)&Ab[(wm + t * 16 + l15) * 64 + ko];
      #pragma unroll
      for (int t = 0; t < 4; t++) bv[t] = *(const short8*)&Bbf[(wn + t * 16 + l15) * 64 + ko];
      #pragma unroll
      for (int ti = 0; ti < 2; ti++)
        #pragma unroll
        for (int tj = 0; tj < 4; tj++)
          acc[ti][tj] = __builtin_amdgcn_mfma_f32_16x16x32_bf16(av[ti], bv[tj], acc[ti][tj], 0, 0, 0);
    }
    __builtin_amdgcn_s_barrier();              // all reads consumed; safe to overwrite cb
  }
  // epilogue: bf16 transpose via Cs, then coalesced store
  #pragma unroll
  for (int ti = 0; ti < 2; ti++) {
    int lr = wm + ti * 16 + quad * 4;
    #pragma unroll
    for (int tj = 0; tj < 4; tj++) {
      int lc = wn + tj * 16 + l15;
      #pragma unroll
      for (int r = 0; r < 4; r++)
        *(bf16*)&Cs[(lr + r) * 136 + lc] = __float2bfloat16(acc[ti][tj][r]);
    }
  }
  __syncthreads();
  int dyq = tau / 3, dxq = tau % 3;
  #pragma unroll
  for (int pass = 0; pass < 4; pass++) {
    int row = pass * 16 + (tid >> 4);          // 0..63
    int col = (tid & 15) * 8;                  // 0..127
    if (tau < 9) {
      *(float4*)&Uc[((size_t)((n * 3 + dyq) * 128 + half * 64 + row)) * 1536 + dxq * 512 + c0 + col] =
          *(const float4*)&Cs[row * 136 + col];
    } else {
      *(float4*)&Usc[((size_t)(n * 128 + half * 64 + row)) * 512 + c0 + col] =
          *(const float4*)&Cs[row * 136 + col];
    }
  }
}

// ---------------- convh: dy-split pipelined GEMM, M=128(o) x N=64(p), K=1536 (conv) / 512 (sc)
__global__ __launch_bounds__(256) void k_convh(const short* __restrict__ Uc,
                                               const short* __restrict__ Usc,
                                               const short* __restrict__ Zpad,
                                               float* __restrict__ Hpart) {
  __shared__ __align__(16) short smem[24576];  // As[2][8192] | Bs[2][4096]  (48 KB)
  short* As = smem;
  short* Bs = smem + 16384;
  int b = blockIdx.x;
  int wgid = (b & 7) * 125 + (b >> 3);         // bijective, 1000 % 8 == 0
  int n = wgid / 100, rest = wgid % 100;
  int dy = rest / 25, pt = rest % 25;
  int p0 = pt * 64;
  int tid = threadIdx.x, lane = tid & 63, wave = tid >> 6;
  int quad = lane >> 4, l15 = lane & 15;
  int wm = (wave & 1) * 64, wn = (wave >> 1) * 32;
  // staging: pre-swizzled global source; LDS stays linear (rule #21)
  int sk = ((tid & 7) ^ ((tid >> 3) & 7)) * 8;   // swizzled 16B-chunk (shorts)
  int rowg = tid >> 3;                            // 0..31
  bool isconv = (dy < 3);
  const short* Zb = Zpad + (size_t)n * KPW * KPW * KC;
  const short* Abase = isconv ? Uc + ((size_t)((n * 3 + dy) * 128)) * 1536
                              : Usc + ((size_t)(n * 128)) * 512;
  int astr = isconv ? 1536 : 512;
  const short* pA[4];
  #pragma unroll
  for (int g = 0; g < 4; g++)
    pA[g] = Abase + (size_t)(g * 32 + rowg) * astr + sk;
  const short* pB[2];
  #pragma unroll
  for (int g = 0; g < 2; g++) {
    int p = p0 + g * 32 + rowg;
    int y = p / KH, x = p % KH;
    int yy = isconv ? (y + dy) : (y + 1);
    int xx = isconv ? x : (x + 1);
    pB[g] = Zb + ((size_t)yy * KPW + xx) * KC + sk;
  }
  char* lA = (char*)As + tid * 16;
  char* lB = (char*)Bs + tid * 16;
  int NS = isconv ? 24 : 8;
  // swizzled ds_read k offsets (shorts)
  int bq = (l15 >> 2) & 1;
  int qx = (quad ^ (l15 & 3)) * 8;
  int koff0 = 32 * bq + qx;
  int koff1 = 32 * (1 - bq) + qx;
  f32x4 acc[4][2] = {};
  // prologue: stage step 0 into buf 0
  gload16(pA[0], lA); gload16(pA[1], lA + 4096);
  gload16(pA[2], lA + 8192); gload16(pA[3], lA + 12288);
  gload16(pB[0], lB); gload16(pB[1], lB + 4096);
  for (int s = 0; s < NS; s++) {
    int cb = s & 1, nb = cb ^ 1;
    if (s + 1 < NS) {
      int off = (s + 1) * 64;
      char* la = lA + nb * 16384;
      char* lb = lB + nb * 8192;
      gload16(pA[0] + off, la); gload16(pA[1] + off, la + 4096);
      gload16(pA[2] + off, la + 8192); gload16(pA[3] + off, la + 12288);
      gload16(pB[0] + off, lb); gload16(pB[1] + off, lb + 4096);
      asm volatile("s_waitcnt vmcnt(6)" ::: "memory");   // current buf done; next 6 in flight
    } else {
      asm volatile("s_waitcnt vmcnt(0)" ::: "memory");
    }
    __builtin_amdgcn_s_barrier();
    __builtin_amdgcn_sched_barrier(0);
    const short* Ab = As + cb * 8192;
    const short* Bb = Bs + cb * 4096;
    #pragma unroll
    for (int ks = 0; ks < 2; ks++) {
      int ko = (ks == 0) ? koff0 : koff1;
      short8 av[4], bv[2];
      #pragma unroll
      for (int t = 0; t < 4; t++) av[t] = *(const short8*)&Ab[(wm + t * 16 + l15) * 64 + ko];
      #pragma unroll
      for (int t = 0; t < 2; t++) bv[t] = *(const short8*)&Bb[(wn + t * 16 + l15) * 64 + ko];
      #pragma unroll
      for (int ti = 0; ti < 4; ti++)
        #pragma unroll
        for (int tj = 0; tj < 2; tj++)
          acc[ti][tj] = __builtin_amdgcn_mfma_f32_16x16x32_bf16(av[ti], bv[tj], acc[ti][tj], 0, 0, 0);
    }
    __builtin_amdgcn_s_barrier();              // lgkm drained before MFMA; safe to overwrite cb
  }
  float* cbp = Hpart + ((size_t)(dy * KN + n)) * KOC * KHW;
  #pragma unroll
  for (int ti = 0; ti < 4; ti++) {
    int o = wm + ti * 16 + quad * 4;
    #pragma unroll
    for (int tj = 0; tj < 2; tj++) {
      int q = p0 + wn + tj * 16 + l15;
      #pragma unroll
      for (int r = 0; r < 4; r++)
        cbp[(size_t)(o + r) * KHW + q] = acc[ti][tj][r];
    }
  }
}

// hpadT[n, y+1, x+1, o] = bf16(relu(b1[o] + Hpart[0]+Hpart[1]+Hpart[2]))
__global__ void k_hprep3(const float* __restrict__ Hpart, const float* __restrict__ b1,
                         bf16* __restrict__ hpadT) {
  __shared__ float T[32][132];
  int n = blockIdx.y, p0 = blockIdx.x * 32;
  int tx = threadIdx.x, ty = threadIdx.y;
  const size_t str = (size_t)KN * KOC * KHW;
  const float* hb = Hpart + (size_t)n * KOC * KHW;
  #pragma unroll
  for (int oc = 0; oc < 16; oc++) {
    int o = oc * 8 + ty;
    size_t off = (size_t)o * KHW + p0 + tx;
    T[tx][o] = fmaxf(hb[off] + hb[str + off] + hb[2 * str + off] + b1[o], 0.0f);
  }
  __syncthreads();
  bf16* hp = hpadT + (size_t)n * KPW * KPW * KOC;
  #pragma unroll
  for (int pc = 0; pc < 4; pc++) {
    int pl = ty * 4 + pc;
    int pp = p0 + pl;
    int yy = pp / KH, xx = pp % KH;
    bf16* row = hp + ((size_t)(yy + 1) * KPW + (xx + 1)) * KOC;
    #pragma unroll
    for (int u = 0; u < 4; u++) row[tx * 4 + u] = __float2bfloat16(T[pl][tx * 4 + u]);
  }
}

// ---------------- conv2 (3x3, 128->128): same pipelined template, K=384 per dy ----------------
// 750 blocks = 10n * 3dy * 25pt, bijective XCD swizzle (750 = 8*93+6).
__global__ __launch_bounds__(256) void k_conv2(const short* __restrict__ w2p,
                                               const short* __restrict__ hpadT,
                                               float* __restrict__ Cpart) {
  __shared__ __align__(16) short smem[24576];
  short* As = smem;
  short* Bs = smem + 16384;
  int b = blockIdx.x;
  int xcd = b & 7, bi = b >> 3;
  int wgid = (xcd < 6 ? xcd * 94 : 6 * 94 + (xcd - 6) * 93) + bi;
  int n = wgid / 75, rest = wgid % 75;
  int dy = rest / 25, pt = rest % 25;
  int p0 = pt * 64;
  int tid = threadIdx.x, lane = tid & 63, wave = tid >> 6;
  int quad = lane >> 4, l15 = lane & 15;
  int wm = (wave & 1) * 64, wn = (wave >> 1) * 32;
  int sk = ((tid & 7) ^ ((tid >> 3) & 7)) * 8;
  int rowg = tid >> 3;
  const short* hb = hpadT + (size_t)n * KPW * KPW * KOC;
  const short* pA[4];
  #pragma unroll
  for (int g = 0; g < 4; g++)
    pA[g] = w2p + (size_t)(g * 32 + rowg) * (9 * KOC) + dy * 384 + sk;
  const short* pB[2];
  #pragma unroll
  for (int g = 0; g < 2; g++) {
    int p = p0 + g * 32 + rowg;
    int y = p / KH, x = p % KH;
    pB[g] = hb + ((size_t)(y + dy) * KPW + x) * KOC + sk;   // k = dx*128+c contiguous
  }
  char* lA = (char*)As + tid * 16;
  char* lB = (char*)Bs + tid * 16;
  const int NS = 6;                            // K = 384 = 6 * 64
  int bq = (l15 >> 2) & 1;
  int qx = (quad ^ (l15 & 3)) * 8;
  int koff0 = 32 * bq + qx;
  int koff1 = 32 * (1 - bq) + qx;
  f32x4 acc[4][2] = {};
  gload16(pA[0], lA); gload16(pA[1], lA + 4096);
  gload16(pA[2], lA + 8192); gload16(pA[3], lA + 12288);
  gload16(pB[0], lB); gload16(pB[1], lB + 4096);
  for (int s = 0; s < NS; s++) {
    int cb = s & 1, nb = cb ^ 1;
    if (s + 1 < NS) {
      int off = (s + 1) * 64;
      char* la = lA + nb * 16384;
      char* lb = lB + nb * 8192;
      gload16(pA[0] + off, la); gload16(pA[1] + off, la + 4096);
      gload16(pA[2] + off, la + 8192); gload16(pA[3] + off, la + 12288);
      gload16(pB[0] + off, lb); gload16(pB[1] + off, lb + 4096);
      asm volatile("s_waitcnt vmcnt(6)" ::: "memory");
    } else {
      asm volatile("s_waitcnt vmcnt(0)" ::: "memory");
    }
    __builtin_amdgcn_s_barrier();
    __builtin_amdgcn_sched_barrier(0);
    const short* Ab = As + cb * 8192;
    const short* Bb = Bs + cb * 4096;
    #pragma unroll
    for (int ks = 0; ks < 2; ks++) {
      int ko = (ks == 0) ? koff0 : koff1;
      short8 av[4], bv[2];
      #pragma unroll
      for (int t = 0; t < 4; t++) av[t] = *(const short8*)&Ab[(wm + t * 16 + l15) * 64 + ko];
      #pragma unroll
      for (int t = 0; t < 2; t++) bv[t] = *(const short8*)&Bb[(wn + t * 16 + l15) * 64 + ko];
      #pragma unroll
      for (int ti = 0; ti < 4; ti++)
        #pragma unroll
        for (int tj = 0; tj < 2; tj++)
          acc[ti][tj] = __builtin_amdgcn_mfma_f32_16x16x32_bf16(av[ti], bv[tj], acc[ti][tj], 0, 0, 0);
    }
    __builtin_amdgcn_s_barrier();
  }
  float* cbp = Cpart + ((size_t)(dy * KN + n)) * KOC * KHW;
  #pragma unroll
  for (int ti = 0; ti < 4; ti++) {
    int o = wm + ti * 16 + quad * 4;
    #pragma unroll
    for (int tj = 0; tj < 2; tj++) {
      int q = p0 + wn + tj * 16 + l15;
      #pragma unroll
      for (int r = 0; r < 4; r++)
        cbp[(size_t)(o + r) * KHW + q] = acc[ti][tj][r];
    }
  }
}

// out = relu(sum_dy Cpart + b2 + shortcut(Hpart[3]) + bs)
__global__ void k_final2(const float* __restrict__ Cpart, const float* __restrict__ Hpart,
                         const float* __restrict__ b2, const float* __restrict__ bs,
                         float* __restrict__ out) {
  int t = blockIdx.x * 256 + threadIdx.x;
  if (t >= KN * KOC * KHW) return;
  int o = (t / KHW) % KOC;
  const size_t stride = (size_t)KN * KOC * KHW;
  float v = Cpart[t] + Cpart[stride + t] + Cpart[2 * stride + t] +
            Hpart[3 * stride + t] + b2[o] + bs[o];
  out[t] = fmaxf(v, 0.0f);
}

// ---------------- launch ----------------
extern "C" void kernel_launch(void* const* d_in, const int* in_sizes, int n_in,
                              void* d_out, int out_size, void* d_ws, size_t ws_size,
                              hipStream_t stream) {
  const float* feats = (const float*)d_in[0];
  const float* sisms = (const float*)d_in[1];
  const float* w1 = (const float*)d_in[2];
  const float* b1 = (const float*)d_in[3];
  const float* w2 = (const float*)d_in[4];
  const float* b2 = (const float*)d_in[5];
  const float* wsc = (const float*)d_in[6];
  const float* bsc = (const float*)d_in[7];
  float* out = (float*)d_out;

  char* w = (char*)d_ws;
  auto carve = [&](size_t bytes) -> void* {
    void* p = (void*)w;
    w += (bytes + 255) & ~(size_t)255;
    return p;
  };
  bf16* NFT   = (bf16*)carve((size_t)KN * KHW * KC * 2);          // 16.4 MB
  bf16* NFcg  = (bf16*)carve((size_t)KN * KC * KHW * 2);          // 16.4 MB
  bf16* Uc    = (bf16*)carve((size_t)KN * 3 * 128 * 1536 * 2);    // 11.8 MB
  bf16* Usc   = (bf16*)carve((size_t)KN * 128 * 512 * 2);         // 1.3 MB
  bf16* w1s   = (bf16*)carve((size_t)KM * KHW * 2);               // 4.1 MB
  bf16* Zpad  = (bf16*)carve((size_t)KN * KPW * KPW * KC * 2);    // 18.1 MB
  bf16* hpadT = (bf16*)carve((size_t)KN * KPW * KPW * KOC * 2);   // 4.5 MB
  float* Hpart = (float*)carve((size_t)4 * KN * KOC * KHW * 4);   // 32.8 MB
  float* Cpart = (float*)carve((size_t)3 * KN * KOC * KHW * 4);   // 24.6 MB
  bf16* w2p   = (bf16*)carve((size_t)KOC * 9 * KOC * 2);
  double* psbuf = (double*)carve((size_t)16 * KN * KHW * 8);      // 2.05 MB
  double* rnorm = (double*)carve((size_t)KN * KHW * 8);
  double* vpp   = (double*)carve((size_t)KN * KC * 50 * 8);       // 2.05 MB
  double* SIV   = (double*)carve((size_t)KN * KC * 8);
  double* cmp   = (double*)carve((size_t)16 * KN * KN * KHW * 8); // 20.5 MB
  double* cm    = (double*)carve((size_t)KN * KN * KHW * 8);
  double* tbuf  = (double*)carve((size_t)KN * KN * 8);
  double* CSAd  = (double*)carve((size_t)KN * KHW * 8);
  float* CSAf   = (float*)carve((size_t)KN * KHW * 4);
  int* idxb     = (int*)carve((size_t)KN * KHW * 4);

  k_zborder<<<513, 256, 0, stream>>>(Zpad, hpadT);

  k_rnormp<<<dim3(63, 16), 256, 0, stream>>>(feats, psbuf);
  k_rnormc<<<63, 256, 0, stream>>>(psbuf, rnorm);
  k_nft<<<dim3(50, 16, KN), dim3(32, 8), 0, stream>>>(feats, rnorm, sisms, NFT, vpp);
  k_sivnorm2<<<KN, 512, 0, stream>>>(vpp, SIV);
  k_cmP<<<dim3(7, 16, KN), 256, 0, stream>>>(feats, SIV, cmp);
  k_cmBN<<<KN * KN, 512, 0, stream>>>(cmp, rnorm, cm);
  k_st<<<KN * KN, 256, 0, stream>>>(cm, tbuf);
  k_csa<<<KN, 256, 0, stream>>>(cm, tbuf, CSAd, CSAf);
  k_rank<<<1000, 256, 0, stream>>>(CSAd, idxb);

  k_prepw1s<<<KM * KHW / 256, 256, 0, stream>>>(w1, wsc, w1s);
  k_prepw2<<<576, 256, 0, stream>>>(w2, w2p);
  k_gath2<<<dim3(50, 16, KN), dim3(32, 8), 0, stream>>>((const short*)NFT, idxb, (short*)NFcg);
  k_zprep<<<KN * KHW * (KC / 4) / 256, 256, 0, stream>>>(NFT, CSAf, Zpad);

  k_gemmU<<<800, 256, 0, stream>>>((const short*)w1s, (const short*)NFcg, Uc, Usc);
  k_convh<<<1000, 256, 0, stream>>>((const short*)Uc, (const short*)Usc,
                                    (const short*)Zpad, Hpart);
  k_hprep3<<<dim3(50, KN), dim3(32, 8), 0, stream>>>(Hpart, b1, hpadT);
  k_conv2<<<750, 256, 0, stream>>>((const short*)w2p, (const short*)hpadT, Cpart);
  k_final2<<<8000, 256, 0, stream>>>(Cpart, Hpart, b2, bsc, out);
}